// Round 1
// baseline (826.126 us; speedup 1.0000x reference)
//
#include <hip/hip_runtime.h>

// ---------------------------------------------------------------------------
// GConv: heterograph conv via  mean_e(concat(x_src, ef) @ W + b)
//      = (agg_feats @ W[:128] + agg_ef @ W[128:]) / deg + b
// Phases: CSR build (count/scan/fill) -> per-etype wave-per-node aggregation
//         -> per-etype [n_dst,160]x[160,128] fp32 GEMM accumulated into out.
// ---------------------------------------------------------------------------

#define N_OP    50000
#define N_DEV   5000
#define N_NODES 160000      // combined dst space over 5 etypes
#define N_EDGES 2480000     // combined edge space
#define GK      160         // padded K (144 -> 160)

__global__ void zero_int_kernel(int* __restrict__ p, int n) {
    int i = blockIdx.x * 256 + threadIdx.x;
    if (i < n) p[i] = 0;
}

// out is [55000][256]; cols 0..127 = raw feats, 128..255 = 0 (accumulator)
__global__ void init_out_kernel(const float* __restrict__ opf,
                                const float* __restrict__ devf,
                                float* __restrict__ out) {
    size_t i = (size_t)blockIdx.x * 256 + threadIdx.x;   // float4 index
    const size_t total = (size_t)(N_OP + N_DEV) * 64;    // 64 float4 per row
    if (i >= total) return;
    size_t row = i >> 6;
    int q = (int)(i & 63);
    float4 v = make_float4(0.f, 0.f, 0.f, 0.f);
    if (q < 32) {
        if (row < N_OP) v = *(const float4*)&opf[row * 128 + q * 4];
        else            v = *(const float4*)&devf[(row - N_OP) * 128 + q * 4];
    }
    *(float4*)&out[row * 256 + q * 4] = v;
}

__global__ void count_kernel(const int* __restrict__ dst, int* __restrict__ deg,
                             int nodebase, int ne) {
    int e = blockIdx.x * 256 + threadIdx.x;
    if (e < ne) atomicAdd(&deg[nodebase + dst[e]], 1);
}

// chunk = 4096 (256 threads x 16). Per-chunk exclusive scan + chunk total.
__global__ __launch_bounds__(256) void scan_block_kernel(
    const int* __restrict__ deg, int* __restrict__ starts,
    int* __restrict__ bsums, int n) {
    __shared__ int wsum[4];
    int tid = threadIdx.x;
    int base = blockIdx.x * 4096 + tid * 16;
    int v[16];
    int s = 0;
#pragma unroll
    for (int i = 0; i < 16; i++) {
        int idx = base + i;
        int t = (idx < n) ? deg[idx] : 0;
        v[i] = t; s += t;
    }
    int lane = tid & 63, wid = tid >> 6;
    int incl = s;
#pragma unroll
    for (int off = 1; off < 64; off <<= 1) {
        int t = __shfl_up(incl, off, 64);
        if (lane >= off) incl += t;
    }
    if (lane == 63) wsum[wid] = incl;
    __syncthreads();
    int woff = 0;
    for (int w2 = 0; w2 < wid; w2++) woff += wsum[w2];
    int run = woff + incl - s;   // thread-exclusive prefix
#pragma unroll
    for (int i = 0; i < 16; i++) {
        int idx = base + i;
        if (idx < n) starts[idx] = run;
        run += v[i];
    }
    if (tid == 255) bsums[blockIdx.x] = woff + incl;  // block total
}

__global__ void scan_bsums_kernel(int* __restrict__ bsums, int nb) {
    int lane = threadIdx.x;  // single wave of 64
    int v = (lane < nb) ? bsums[lane] : 0;
    int incl = v;
#pragma unroll
    for (int off = 1; off < 64; off <<= 1) {
        int t = __shfl_up(incl, off, 64);
        if (lane >= off) incl += t;
    }
    if (lane < nb) bsums[lane] = incl - v;  // exclusive
}

__global__ void scan_add_kernel(int* __restrict__ starts,
                                const int* __restrict__ bsums, int n) {
    int i = blockIdx.x * 256 + threadIdx.x;
    if (i < n) starts[i] += bsums[i >> 12];   // 4096 per chunk
}

__global__ void fill_kernel(const int* __restrict__ src, const int* __restrict__ dst,
                            const int* __restrict__ starts, int* __restrict__ cursor,
                            int2* __restrict__ edata, int nodebase, int ne) {
    int e = blockIdx.x * 256 + threadIdx.x;
    if (e < ne) {
        int g = nodebase + dst[e];
        int pos = starts[g] + atomicAdd(&cursor[g], 1);
        edata[pos] = make_int2(src[e], e);
    }
}

// One wave per dst node. Lane l accumulates feat dims 2l,2l+1; lanes<16 also
// accumulate 1 ef dim. Writes agg[w][0..143], zeros pad [144..159].
__global__ __launch_bounds__(256) void agg_kernel(
    const float* __restrict__ sf,       // [n_src][128]
    const float* __restrict__ ef,       // [ne][16]
    const int2* __restrict__ edata,     // combined (src, e) records
    const int* __restrict__ starts, const int* __restrict__ deg,
    int nodebase, float* __restrict__ agg, int n_dst) {
    int w = (blockIdx.x * 256 + threadIdx.x) >> 6;
    int lane = threadIdx.x & 63;
    if (w >= n_dst) return;
    int g = nodebase + w;
    int s0 = starts[g], dg = deg[g];
    float a0 = 0.f, a1 = 0.f, aef = 0.f;
    for (int bb = 0; bb < dg; bb += 64) {
        int cnt = min(64, dg - bb);
        int2 ed = make_int2(0, 0);
        if (bb + lane < dg) ed = edata[s0 + bb + lane];
        for (int j = 0; j < cnt; j++) {
            int s = __shfl(ed.x, j, 64);
            int e = __shfl(ed.y, j, 64);
            const float2 f = *(const float2*)&sf[(size_t)s * 128 + lane * 2];
            a0 += f.x; a1 += f.y;
            if (lane < 16) aef += ef[(size_t)e * 16 + lane];
        }
    }
    float* row = &agg[(size_t)w * GK];
    row[lane * 2]     = a0;
    row[lane * 2 + 1] = a1;
    if (lane < 16)       row[128 + lane] = aef;
    else if (lane < 32)  row[128 + lane] = 0.f;   // zero K-pad 144..159
}

// [n_dst,160] x [160, 64(cols per y-block)] fp32 GEMM.
// Block: 64 rows x 64 cols, 256 threads, 4x4 register tile.
// A (full K) in LDS, W staged in two K-halves of 80. Epilogue folds
// mean-div, bias, etype scale; accumulates into strided out; optional ReLU.
__global__ __launch_bounds__(256) void gemm_kernel(
    const float* __restrict__ agg,    // [>=n_dst][160]
    const float* __restrict__ W,      // [144][128]
    const float* __restrict__ bias,   // [128]
    const int* __restrict__ deg,      // deg + nodebase
    float* __restrict__ out,          // row stride 256, col offset 128 applied
    int n_dst, float scale, int finalize) {
    __shared__ float A_s[64][164];    // padded stride: 2-way-max banks
    __shared__ float W_s[80][64];
    int tid = threadIdx.x;
    int rowbase = blockIdx.x * 64;
    int jbase = blockIdx.y * 64;

    // stage A: 64 rows x 40 float4
    for (int i = tid; i < 64 * 40; i += 256) {
        int r = i / 40, q = i % 40;
        int row = rowbase + r;
        float4 a = make_float4(0.f, 0.f, 0.f, 0.f);
        if (row < n_dst) a = *(const float4*)&agg[(size_t)row * GK + q * 4];
        *(float4*)&A_s[r][q * 4] = a;
    }

    int ct = tid & 15, rt = tid >> 4;
    float acc[4][4];
#pragma unroll
    for (int r = 0; r < 4; r++)
#pragma unroll
        for (int c = 0; c < 4; c++) acc[r][c] = 0.f;

    for (int kh = 0; kh < 2; kh++) {
        __syncthreads();   // A ready (kh=0); W_s reads done (kh=1)
        // stage W half: 80 x 16 float4
        for (int i = tid; i < 80 * 16; i += 256) {
            int kl = i >> 4, j4 = (i & 15) << 2;
            int gk = kh * 80 + kl;
            float4 wv = make_float4(0.f, 0.f, 0.f, 0.f);
            if (gk < 144) wv = *(const float4*)&W[(size_t)gk * 128 + jbase + j4];
            *(float4*)&W_s[kl][j4] = wv;
        }
        __syncthreads();
        int kbase = kh * 80;
#pragma unroll 4
        for (int kk = 0; kk < 80; kk += 4) {
            float4 w0 = *(const float4*)&W_s[kk + 0][ct * 4];
            float4 w1 = *(const float4*)&W_s[kk + 1][ct * 4];
            float4 w2 = *(const float4*)&W_s[kk + 2][ct * 4];
            float4 w3 = *(const float4*)&W_s[kk + 3][ct * 4];
            float4 a0 = *(const float4*)&A_s[rt * 4 + 0][kbase + kk];
            float4 a1 = *(const float4*)&A_s[rt * 4 + 1][kbase + kk];
            float4 a2 = *(const float4*)&A_s[rt * 4 + 2][kbase + kk];
            float4 a3 = *(const float4*)&A_s[rt * 4 + 3][kbase + kk];
#define DOROW(r, av)                                                  \
            acc[r][0] += av.x * w0.x + av.y * w1.x + av.z * w2.x + av.w * w3.x; \
            acc[r][1] += av.x * w0.y + av.y * w1.y + av.z * w2.y + av.w * w3.y; \
            acc[r][2] += av.x * w0.z + av.y * w1.z + av.z * w2.z + av.w * w3.z; \
            acc[r][3] += av.x * w0.w + av.y * w1.w + av.z * w2.w + av.w * w3.w;
            DOROW(0, a0) DOROW(1, a1) DOROW(2, a2) DOROW(3, a3)
#undef DOROW
        }
    }

    float4 bv = *(const float4*)&bias[jbase + ct * 4];
#pragma unroll
    for (int r = 0; r < 4; r++) {
        int row = rowbase + rt * 4 + r;
        if (row >= n_dst) continue;
        int dg = deg[row];
        float inv = (dg > 0) ? scale / (float)dg : 0.f;
        float bs  = (dg > 0) ? scale : 0.f;
        float4 v;
        v.x = acc[r][0] * inv + bs * bv.x;
        v.y = acc[r][1] * inv + bs * bv.y;
        v.z = acc[r][2] * inv + bs * bv.z;
        v.w = acc[r][3] * inv + bs * bv.w;
        float* po = &out[(size_t)row * 256 + 128 + jbase + ct * 4];
        float4 o = *(const float4*)po;
        o.x += v.x; o.y += v.y; o.z += v.z; o.w += v.w;
        if (finalize) {
            o.x = fmaxf(o.x, 0.f); o.y = fmaxf(o.y, 0.f);
            o.z = fmaxf(o.z, 0.f); o.w = fmaxf(o.w, 0.f);
        }
        *(float4*)po = o;
    }
}

extern "C" void kernel_launch(void* const* d_in, const int* in_sizes, int n_in,
                              void* d_out, int out_size, void* d_ws, size_t ws_size,
                              hipStream_t stream) {
    const float* opf  = (const float*)d_in[0];
    const float* devf = (const float*)d_in[1];
    const float* ef[5]; const int* src[5]; const int* dst[5];
    const float* W[5]; const float* bias[5];
    int ne[5];
    for (int i = 0; i < 5; i++) {
        ef[i]   = (const float*)d_in[2 + 5 * i + 0];
        src[i]  = (const int*)  d_in[2 + 5 * i + 1];
        dst[i]  = (const int*)  d_in[2 + 5 * i + 2];
        W[i]    = (const float*)d_in[2 + 5 * i + 3];
        bias[i] = (const float*)d_in[2 + 5 * i + 4];
        ne[i]   = in_sizes[2 + 5 * i + 1];
    }
    // etype order: link(d->d), prev(o->o), succ(o->o), place(o->d), serve(d->o)
    const int n_src_arr[5] = {N_DEV, N_OP, N_OP, N_OP, N_DEV};
    const int n_dst_arr[5] = {N_DEV, N_OP, N_OP, N_DEV, N_OP};
    const int nodebase[5]  = {0, 5000, 55000, 105000, 110000};

    char* wp = (char*)d_ws;
    int* deg    = (int*)wp;  wp += (size_t)N_NODES * 4;
    int* cursor = (int*)wp;  wp += (size_t)N_NODES * 4;   // contiguous w/ deg
    int* starts = (int*)wp;  wp += (size_t)N_NODES * 4;
    int* bsums  = (int*)wp;  wp += 256;
    int2* edata = (int2*)wp; wp += (size_t)N_EDGES * 8;
    float* agg  = (float*)wp;                              // 50000*160 floats
    float* out  = (float*)d_out;

    zero_int_kernel<<<(2 * N_NODES + 255) / 256, 256, 0, stream>>>(deg, 2 * N_NODES);
    init_out_kernel<<<((N_OP + N_DEV) * 64 + 255) / 256, 256, 0, stream>>>(opf, devf, out);

    for (int i = 0; i < 5; i++)
        count_kernel<<<(ne[i] + 255) / 256, 256, 0, stream>>>(dst[i], deg, nodebase[i], ne[i]);

    const int nchunks = (N_NODES + 4095) / 4096;  // 40
    scan_block_kernel<<<nchunks, 256, 0, stream>>>(deg, starts, bsums, N_NODES);
    scan_bsums_kernel<<<1, 64, 0, stream>>>(bsums, nchunks);
    scan_add_kernel<<<(N_NODES + 255) / 256, 256, 0, stream>>>(starts, bsums, N_NODES);

    for (int i = 0; i < 5; i++)
        fill_kernel<<<(ne[i] + 255) / 256, 256, 0, stream>>>(src[i], dst[i], starts, cursor,
                                                             edata, nodebase[i], ne[i]);

    // device-dst first (link, place+relu), then op-dst (prev, succ, serve+relu)
    const int order[5] = {0, 3, 1, 2, 4};
    for (int oi = 0; oi < 5; oi++) {
        int i = order[oi];
        int nd = n_dst_arr[i];
        bool isdev = (nd == N_DEV);
        float scale = isdev ? 0.5f : (1.f / 3.f);
        int fin = (i == 3 || i == 4) ? 1 : 0;
        const float* sf = (n_src_arr[i] == N_DEV) ? devf : opf;
        agg_kernel<<<(nd * 64 + 255) / 256, 256, 0, stream>>>(
            sf, ef[i], edata, starts, deg, nodebase[i], agg, nd);
        float* outb = isdev ? out + (size_t)N_OP * 256 : out;
        dim3 g((nd + 63) / 64, 2);
        gemm_kernel<<<g, 256, 0, stream>>>(agg, W[i], bias[i], deg + nodebase[i],
                                           outb, nd, scale, fin);
    }
    (void)n_in; (void)out_size; (void)ws_size;
}

// Round 2
// 532.731 us; speedup vs baseline: 1.5507x; 1.5507x over previous
//
#include <hip/hip_runtime.h>
#include <hip/hip_bf16.h>

// ---------------------------------------------------------------------------
// GConv via  mean_e(concat(x_src, ef) @ W + b) = mean_feats @ W + b*mask
// Phases: bf16 convert -> CSR build (fused count/scan/fill) ->
//         fused group-gather aggregation (bf16 means, 1 dispatch) ->
//         fused concat-K GEMM (op K=480, dev K=320, 1 dispatch) + ReLU.
// ---------------------------------------------------------------------------

#define N_OP    50000
#define N_DEV   5000
#define N_NODES 160000
// node-space bases: link(dev) 0, prev(op) 5000, succ(op) 55000,
//                   place(dev) 105000, serve(op) 110000
#define NB0 0
#define NB1 5000
#define NB2 55000
#define NB3 105000
#define NB4 110000

typedef unsigned short u16;
typedef __attribute__((ext_vector_type(8))) unsigned short u16x8;

__device__ __forceinline__ u16 bf16rn(float x) {
    unsigned u = __float_as_uint(x);
    return (u16)((u + 0x7fffu + ((u >> 16) & 1u)) >> 16);
}
__device__ __forceinline__ float bf2f(u16 h) {
    return __uint_as_float((unsigned)h << 16);
}

__global__ void zero_int_kernel(int* __restrict__ p, int n) {
    int i = blockIdx.x * 256 + threadIdx.x;
    if (i < n) p[i] = 0;
}

// fp32 feats -> bf16 (op then dev), 8 elems/thread
__global__ void conv_bf16_kernel(const float* __restrict__ opf,
                                 const float* __restrict__ devf,
                                 u16* __restrict__ opb, u16* __restrict__ devb) {
    int i = blockIdx.x * 256 + threadIdx.x;         // 8-elem group index
    const int n_op8 = N_OP * 128 / 8, n_tot8 = (N_OP + N_DEV) * 128 / 8;
    if (i >= n_tot8) return;
    const float* s; u16* d; size_t off;
    if (i < n_op8) { s = opf; d = opb; off = (size_t)i * 8; }
    else           { s = devf; d = devb; off = (size_t)(i - n_op8) * 8; }
    float4 x = *(const float4*)&s[off];
    float4 y = *(const float4*)&s[off + 4];
    u16x8 o;
    o[0] = bf16rn(x.x); o[1] = bf16rn(x.y); o[2] = bf16rn(x.z); o[3] = bf16rn(x.w);
    o[4] = bf16rn(y.x); o[5] = bf16rn(y.y); o[6] = bf16rn(y.z); o[7] = bf16rn(y.w);
    *(u16x8*)&d[off] = o;
}

// copy raw feats (exact fp32) into left half of out rows
__global__ void copy_left_kernel(const float* __restrict__ opf,
                                 const float* __restrict__ devf,
                                 float* __restrict__ out) {
    int i = blockIdx.x * 256 + threadIdx.x;          // float4 index
    const int tot = (N_OP + N_DEV) * 32;
    if (i >= tot) return;
    int row = i >> 5, q = i & 31;
    float4 v;
    if (row < N_OP) v = *(const float4*)&opf[(size_t)row * 128 + q * 4];
    else            v = *(const float4*)&devf[(size_t)(row - N_OP) * 128 + q * 4];
    *(float4*)&out[(size_t)row * 256 + q * 4] = v;
}

__global__ void count_all_kernel(const int* __restrict__ d0, const int* __restrict__ d1,
                                 const int* __restrict__ d2, const int* __restrict__ d3,
                                 const int* __restrict__ d4,
                                 int e1, int e2, int e3, int e4, int ntot,
                                 int* __restrict__ deg) {
    int e = blockIdx.x * 256 + threadIdx.x;
    if (e >= ntot) return;
    const int* dp; int nb, eb;
    if (e < e1)      { dp = d0; nb = NB0; eb = 0; }
    else if (e < e2) { dp = d1; nb = NB1; eb = e1; }
    else if (e < e3) { dp = d2; nb = NB2; eb = e2; }
    else if (e < e4) { dp = d3; nb = NB3; eb = e3; }
    else             { dp = d4; nb = NB4; eb = e4; }
    atomicAdd(&deg[nb + dp[e - eb]], 1);
}

// chunk = 4096 (256 threads x 16). Per-chunk exclusive scan + chunk total.
__global__ __launch_bounds__(256) void scan_block_kernel(
    const int* __restrict__ deg, int* __restrict__ starts,
    int* __restrict__ bsums, int n) {
    __shared__ int wsum[4];
    int tid = threadIdx.x;
    int base = blockIdx.x * 4096 + tid * 16;
    int v[16];
    int s = 0;
#pragma unroll
    for (int i = 0; i < 16; i++) {
        int idx = base + i;
        int t = (idx < n) ? deg[idx] : 0;
        v[i] = t; s += t;
    }
    int lane = tid & 63, wid = tid >> 6;
    int incl = s;
#pragma unroll
    for (int off = 1; off < 64; off <<= 1) {
        int t = __shfl_up(incl, off, 64);
        if (lane >= off) incl += t;
    }
    if (lane == 63) wsum[wid] = incl;
    __syncthreads();
    int woff = 0;
    for (int w2 = 0; w2 < wid; w2++) woff += wsum[w2];
    int run = woff + incl - s;
#pragma unroll
    for (int i = 0; i < 16; i++) {
        int idx = base + i;
        if (idx < n) starts[idx] = run;
        run += v[i];
    }
    if (tid == 255) bsums[blockIdx.x] = woff + incl;
}

__global__ void scan_bsums_kernel(int* __restrict__ bsums, int nb) {
    int lane = threadIdx.x;
    int v = (lane < nb) ? bsums[lane] : 0;
    int incl = v;
#pragma unroll
    for (int off = 1; off < 64; off <<= 1) {
        int t = __shfl_up(incl, off, 64);
        if (lane >= off) incl += t;
    }
    if (lane < nb) bsums[lane] = incl - v;
}

__global__ void scan_add_kernel(int* __restrict__ starts,
                                const int* __restrict__ bsums, int n) {
    int i = blockIdx.x * 256 + threadIdx.x;
    if (i < n) starts[i] += bsums[i >> 12];
}

__global__ void fill_all_kernel(const int* __restrict__ s0p, const int* __restrict__ s1p,
                                const int* __restrict__ s2p, const int* __restrict__ s3p,
                                const int* __restrict__ s4p,
                                const int* __restrict__ d0, const int* __restrict__ d1,
                                const int* __restrict__ d2, const int* __restrict__ d3,
                                const int* __restrict__ d4,
                                int e1, int e2, int e3, int e4, int ntot,
                                const int* __restrict__ starts, int* __restrict__ cursor,
                                int2* __restrict__ edata) {
    int e = blockIdx.x * 256 + threadIdx.x;
    if (e >= ntot) return;
    const int* sp; const int* dp; int nb, eb;
    if (e < e1)      { sp = s0p; dp = d0; nb = NB0; eb = 0; }
    else if (e < e2) { sp = s1p; dp = d1; nb = NB1; eb = e1; }
    else if (e < e3) { sp = s2p; dp = d2; nb = NB2; eb = e2; }
    else if (e < e4) { sp = s3p; dp = d3; nb = NB3; eb = e3; }
    else             { sp = s4p; dp = d4; nb = NB4; eb = e4; }
    int el = e - eb;
    int g = nb + dp[el];
    int pos = starts[g] + atomicAdd(&cursor[g], 1);
    edata[pos] = make_int2(sp[el], el);
}

// One wave per dst node over combined 160000-node space.
// Wave = 4 groups of 16 lanes; each group owns one edge per step (x2 unroll);
// lane gl covers feat dims gl*8..gl*8+7 (16B bf16 load) and ef dim gl.
// Group partial sums reduced via shfl_xor(16/32). Stores MEAN row as bf16[160].
__global__ __launch_bounds__(256) void agg_all_kernel(
    const u16* __restrict__ opb, const u16* __restrict__ devb,
    const float* __restrict__ ef0, const float* __restrict__ ef1,
    const float* __restrict__ ef2, const float* __restrict__ ef3,
    const float* __restrict__ ef4,
    const int2* __restrict__ edata, const int* __restrict__ starts,
    const int* __restrict__ deg, u16* __restrict__ agg) {
    int w = (blockIdx.x * 256 + threadIdx.x) >> 6;   // node id (grid exact)
    int lane = threadIdx.x & 63;
    int grp = lane >> 4, gl = lane & 15;
    const u16* sf; const float* efp;
    if (w < NB1)      { sf = devb; efp = ef0; }
    else if (w < NB2) { sf = opb;  efp = ef1; }
    else if (w < NB3) { sf = opb;  efp = ef2; }
    else if (w < NB4) { sf = opb;  efp = ef3; }
    else              { sf = devb; efp = ef4; }
    int s0 = starts[w], dg = deg[w];
    float a[8] = {0.f, 0.f, 0.f, 0.f, 0.f, 0.f, 0.f, 0.f};
    float aef = 0.f;
    for (int bb = 0; bb < dg; bb += 8) {
        int i0 = bb + grp, i1 = bb + 4 + grp;
        if (i0 < dg) {
            int2 ed = edata[s0 + i0];
            u16x8 f = *(const u16x8*)&sf[(size_t)ed.x * 128 + gl * 8];
#pragma unroll
            for (int t = 0; t < 8; t++) a[t] += bf2f(f[t]);
            aef += efp[(size_t)ed.y * 16 + gl];
        }
        if (i1 < dg) {
            int2 ed = edata[s0 + i1];
            u16x8 f = *(const u16x8*)&sf[(size_t)ed.x * 128 + gl * 8];
#pragma unroll
            for (int t = 0; t < 8; t++) a[t] += bf2f(f[t]);
            aef += efp[(size_t)ed.y * 16 + gl];
        }
    }
#pragma unroll
    for (int t = 0; t < 8; t++) {
        a[t] += __shfl_xor(a[t], 16);
        a[t] += __shfl_xor(a[t], 32);
    }
    aef += __shfl_xor(aef, 16);
    aef += __shfl_xor(aef, 32);
    float inv = (dg > 0) ? 1.f / (float)dg : 0.f;
    u16* row = &agg[(size_t)w * 160];
    if (lane < 16) {
        u16x8 o;
#pragma unroll
        for (int t = 0; t < 8; t++) o[t] = bf16rn(a[t] * inv);
        *(u16x8*)&row[gl * 8] = o;
        row[128 + gl] = bf16rn(aef * inv);
    } else if (lane < 32) {
        row[144 + gl] = 0;                 // zero K-pad 144..159
    }
}

// Fused concat-K GEMM. Block tile 64 rows x 128 cols, thread tile 4x8
// (cols ct*4 and 64+ct*4). A from bf16 agg (K chunks of 80, each inside one
// 160-wide segment), W fp32 staged. Epilogue: *scale + masked bias, ReLU,
// write-only store to out right half. Grid = op blocks then dev blocks.
__global__ __launch_bounds__(256) void gemm_all_kernel(
    const u16* __restrict__ agg,
    const float* __restrict__ Wl, const float* __restrict__ Wp,
    const float* __restrict__ Ws, const float* __restrict__ Wpl,
    const float* __restrict__ Wsv,
    const float* __restrict__ bl, const float* __restrict__ bp,
    const float* __restrict__ bs, const float* __restrict__ bpl,
    const float* __restrict__ bsv,
    const int* __restrict__ deg,
    float* __restrict__ out, int opblocks) {
    __shared__ float A_s[64][84];
    __shared__ float W_s[80][128];
    int tid = threadIdx.x;
    int bid = blockIdx.x;
    bool isop = bid < opblocks;
    int rowbase, n_dst, nseg, sb0_, sb1_, sb2_, outrow0;
    const float *W0, *W1, *W2, *B0, *B1, *B2;
    float scale;
    if (isop) {
        rowbase = bid * 64; n_dst = N_OP; nseg = 3;
        sb0_ = NB1; sb1_ = NB2; sb2_ = NB4;
        W0 = Wp; W1 = Ws; W2 = Wsv; B0 = bp; B1 = bs; B2 = bsv;
        scale = 1.f / 3.f; outrow0 = 0;
    } else {
        rowbase = (bid - opblocks) * 64; n_dst = N_DEV; nseg = 2;
        sb0_ = NB0; sb1_ = NB3; sb2_ = NB3;
        W0 = Wl; W1 = Wpl; W2 = Wpl; B0 = bl; B1 = bpl; B2 = bpl;
        scale = 0.5f; outrow0 = N_OP;
    }
    int ct = tid & 15, rt = tid >> 4;
    float acc[4][8];
#pragma unroll
    for (int r = 0; r < 4; r++)
#pragma unroll
        for (int c = 0; c < 8; c++) acc[r][c] = 0.f;

    int nchunk = nseg * 2;
    for (int c = 0; c < nchunk; c++) {
        int seg = c >> 1, koff = (c & 1) * 80;
        int segbase = (seg == 0) ? sb0_ : ((seg == 1) ? sb1_ : sb2_);
        const float* Wc = (seg == 0) ? W0 : ((seg == 1) ? W1 : W2);
        __syncthreads();   // previous chunk's LDS reads complete
        // stage A: 64 rows x 80 bf16 (10 x 16B per row)
        for (int i = tid; i < 640; i += 256) {
            int r = i / 10, q = i % 10;
            int row = rowbase + r;
            u16x8 v = {0, 0, 0, 0, 0, 0, 0, 0};
            if (row < n_dst)
                v = *(const u16x8*)&agg[(size_t)(segbase + row) * 160 + koff + q * 8];
#pragma unroll
            for (int t = 0; t < 8; t++) A_s[r][q * 8 + t] = bf2f(v[t]);
        }
        // stage W: 80 x 128 fp32 (k rows >=144 are zero)
        for (int i = tid; i < 2560; i += 256) {
            int kl = i >> 5, j4 = (i & 31) * 4;
            int gk = koff + kl;
            float4 wv = make_float4(0.f, 0.f, 0.f, 0.f);
            if (gk < 144) wv = *(const float4*)&Wc[(size_t)gk * 128 + j4];
            *(float4*)&W_s[kl][j4] = wv;
        }
        __syncthreads();
        for (int kk = 0; kk < 80; kk += 4) {
            float4 av0 = *(const float4*)&A_s[rt * 4 + 0][kk];
            float4 av1 = *(const float4*)&A_s[rt * 4 + 1][kk];
            float4 av2 = *(const float4*)&A_s[rt * 4 + 2][kk];
            float4 av3 = *(const float4*)&A_s[rt * 4 + 3][kk];
            int kkt = kk;
#define ROW8(r, a) \
            acc[r][0] += (a) * wl.x; acc[r][1] += (a) * wl.y; \
            acc[r][2] += (a) * wl.z; acc[r][3] += (a) * wl.w; \
            acc[r][4] += (a) * wh.x; acc[r][5] += (a) * wh.y; \
            acc[r][6] += (a) * wh.z; acc[r][7] += (a) * wh.w;
#define TSTEP(comp) { \
            float4 wl = *(const float4*)&W_s[kkt][ct * 4]; \
            float4 wh = *(const float4*)&W_s[kkt][64 + ct * 4]; \
            ROW8(0, av0.comp) ROW8(1, av1.comp) \
            ROW8(2, av2.comp) ROW8(3, av3.comp) \
            kkt++; }
            TSTEP(x) TSTEP(y) TSTEP(z) TSTEP(w)
#undef TSTEP
#undef ROW8
        }
    }

    // epilogue
    float4 b0l = *(const float4*)&B0[ct * 4];
    float4 b0h = *(const float4*)&B0[64 + ct * 4];
    float4 b1l = *(const float4*)&B1[ct * 4];
    float4 b1h = *(const float4*)&B1[64 + ct * 4];
    float4 b2l = make_float4(0.f, 0.f, 0.f, 0.f);
    float4 b2h = make_float4(0.f, 0.f, 0.f, 0.f);
    if (nseg == 3) {
        b2l = *(const float4*)&B2[ct * 4];
        b2h = *(const float4*)&B2[64 + ct * 4];
    }
#pragma unroll
    for (int r = 0; r < 4; r++) {
        int row = rowbase + rt * 4 + r;
        if (row >= n_dst) continue;
        float m0 = (deg[sb0_ + row] > 0) ? scale : 0.f;
        float m1 = (deg[sb1_ + row] > 0) ? scale : 0.f;
        float m2 = (nseg == 3 && deg[sb2_ + row] > 0) ? scale : 0.f;
        float4 vlo, vhi;
        vlo.x = acc[r][0] * scale + m0 * b0l.x + m1 * b1l.x + m2 * b2l.x;
        vlo.y = acc[r][1] * scale + m0 * b0l.y + m1 * b1l.y + m2 * b2l.y;
        vlo.z = acc[r][2] * scale + m0 * b0l.z + m1 * b1l.z + m2 * b2l.z;
        vlo.w = acc[r][3] * scale + m0 * b0l.w + m1 * b1l.w + m2 * b2l.w;
        vhi.x = acc[r][4] * scale + m0 * b0h.x + m1 * b1h.x + m2 * b2h.x;
        vhi.y = acc[r][5] * scale + m0 * b0h.y + m1 * b1h.y + m2 * b2h.y;
        vhi.z = acc[r][6] * scale + m0 * b0h.z + m1 * b1h.z + m2 * b2h.z;
        vhi.w = acc[r][7] * scale + m0 * b0h.w + m1 * b1h.w + m2 * b2h.w;
        vlo.x = fmaxf(vlo.x, 0.f); vlo.y = fmaxf(vlo.y, 0.f);
        vlo.z = fmaxf(vlo.z, 0.f); vlo.w = fmaxf(vlo.w, 0.f);
        vhi.x = fmaxf(vhi.x, 0.f); vhi.y = fmaxf(vhi.y, 0.f);
        vhi.z = fmaxf(vhi.z, 0.f); vhi.w = fmaxf(vhi.w, 0.f);
        float* po = out + (size_t)(outrow0 + row) * 256 + 128;
        *(float4*)(po + ct * 4) = vlo;
        *(float4*)(po + 64 + ct * 4) = vhi;
    }
}

extern "C" void kernel_launch(void* const* d_in, const int* in_sizes, int n_in,
                              void* d_out, int out_size, void* d_ws, size_t ws_size,
                              hipStream_t stream) {
    const float* opf  = (const float*)d_in[0];
    const float* devf = (const float*)d_in[1];
    const float* ef[5]; const int* src[5]; const int* dst[5];
    const float* W[5]; const float* bias[5];
    int ne[5];
    for (int i = 0; i < 5; i++) {
        ef[i]   = (const float*)d_in[2 + 5 * i + 0];
        src[i]  = (const int*)  d_in[2 + 5 * i + 1];
        dst[i]  = (const int*)  d_in[2 + 5 * i + 2];
        W[i]    = (const float*)d_in[2 + 5 * i + 3];
        bias[i] = (const float*)d_in[2 + 5 * i + 4];
        ne[i]   = in_sizes[2 + 5 * i + 1];
    }
    int e1 = ne[0], e2 = e1 + ne[1], e3 = e2 + ne[2], e4 = e3 + ne[3];
    int ntot = e4 + ne[4];
    int ntot_pad = (ntot + 1) & ~1;

    char* wp = (char*)d_ws;
    int* deg    = (int*)wp;  wp += (size_t)N_NODES * 4;
    int* cursor = (int*)wp;  wp += (size_t)N_NODES * 4;   // contiguous w/ deg
    int* starts = (int*)wp;  wp += (size_t)N_NODES * 4;
    int* bsums  = (int*)wp;  wp += 256;
    int2* edata = (int2*)wp; wp += (size_t)ntot_pad * 8;
    u16* aggb   = (u16*)wp;  wp += (size_t)N_NODES * 160 * 2;
    u16* opb    = (u16*)wp;  wp += (size_t)N_OP * 128 * 2;
    u16* devb   = (u16*)wp;
    float* out  = (float*)d_out;

    zero_int_kernel<<<(2 * N_NODES + 255) / 256, 256, 0, stream>>>(deg, 2 * N_NODES);
    conv_bf16_kernel<<<((N_OP + N_DEV) * 16 + 255) / 256, 256, 0, stream>>>(
        opf, devf, opb, devb);
    copy_left_kernel<<<((N_OP + N_DEV) * 32 + 255) / 256, 256, 0, stream>>>(
        opf, devf, out);

    count_all_kernel<<<(ntot + 255) / 256, 256, 0, stream>>>(
        dst[0], dst[1], dst[2], dst[3], dst[4], e1, e2, e3, e4, ntot, deg);

    const int nchunks = (N_NODES + 4095) / 4096;  // 40
    scan_block_kernel<<<nchunks, 256, 0, stream>>>(deg, starts, bsums, N_NODES);
    scan_bsums_kernel<<<1, 64, 0, stream>>>(bsums, nchunks);
    scan_add_kernel<<<(N_NODES + 255) / 256, 256, 0, stream>>>(starts, bsums, N_NODES);

    fill_all_kernel<<<(ntot + 255) / 256, 256, 0, stream>>>(
        src[0], src[1], src[2], src[3], src[4],
        dst[0], dst[1], dst[2], dst[3], dst[4],
        e1, e2, e3, e4, ntot, starts, cursor, edata);

    agg_all_kernel<<<N_NODES / 4, 256, 0, stream>>>(
        opb, devb, ef[0], ef[1], ef[2], ef[3], ef[4], edata, starts, deg, aggb);

    int opblocks = (N_OP + 63) / 64, devblocks = (N_DEV + 63) / 64;
    gemm_all_kernel<<<opblocks + devblocks, 256, 0, stream>>>(
        aggb, W[0], W[1], W[2], W[3], W[4],
        bias[0], bias[1], bias[2], bias[3], bias[4],
        deg, out, opblocks);
    (void)n_in; (void)out_size; (void)ws_size;
}

// Round 3
// 489.084 us; speedup vs baseline: 1.6891x; 1.0892x over previous
//
#include <hip/hip_runtime.h>

// ---------------------------------------------------------------------------
// GConv via  mean_e(concat(x_src, ef) @ W + b) = mean_feats @ W + mask*b
// zero -> prep(conv bf16 + copy left + Wt build + degree count) ->
// scan(3) -> fill(CSR) -> agg (4-chain ILP, bf16 means, mask in K-pad) ->
// bf16 MFMA GEMM (op K=480, dev K=320) with bias folded into K=144 slot.
// ---------------------------------------------------------------------------

#define N_OP    50000
#define N_DEV   5000
#define N_NODES 160000
#define NB0 0
#define NB1 5000
#define NB2 55000
#define NB3 105000
#define NB4 110000

typedef unsigned short u16;
typedef unsigned int   u32;
typedef __attribute__((ext_vector_type(8))) unsigned short u16x8;
typedef __attribute__((ext_vector_type(4))) unsigned int   u32x4;
typedef __attribute__((ext_vector_type(8))) short          short8;
typedef __attribute__((ext_vector_type(4))) float          f32x4;

__device__ __forceinline__ u16 bf16rn(float x) {
    unsigned u = __float_as_uint(x);
    return (u16)((u + 0x7fffu + ((u >> 16) & 1u)) >> 16);
}

__global__ void zero_int_kernel(int* __restrict__ p, int n) {
    int i = blockIdx.x * 256 + threadIdx.x;
    if (i < n) p[i] = 0;
}

// Fused: feats->bf16, copy left half of out, build Wt (bf16, transposed,
// bias folded at k=144), degree count.
__global__ __launch_bounds__(256) void prep_kernel(
    const float* __restrict__ opf, const float* __restrict__ devf,
    const float* __restrict__ W0, const float* __restrict__ W1,
    const float* __restrict__ W2, const float* __restrict__ W3,
    const float* __restrict__ W4,
    const float* __restrict__ B0, const float* __restrict__ B1,
    const float* __restrict__ B2, const float* __restrict__ B3,
    const float* __restrict__ B4,
    const int* __restrict__ d0, const int* __restrict__ d1,
    const int* __restrict__ d2, const int* __restrict__ d3,
    const int* __restrict__ d4,
    int e1, int e2, int e3, int e4, int ntot,
    u16* __restrict__ opb, u16* __restrict__ devb,
    float* __restrict__ out, u16* __restrict__ wtop, u16* __restrict__ wtdev,
    int* __restrict__ deg) {
    const int NU0 = (N_OP + N_DEV) * 16;   // conv units (8 elems)
    const int NU1 = (N_OP + N_DEV) * 32;   // copy units (float4)
    const int NU2 = 128 * 480 + 128 * 320; // wt elems
    int t = blockIdx.x * 256 + threadIdx.x;
    if (t < NU0) {
        const int n_op8 = N_OP * 16;
        const float* s; u16* d; size_t off;
        if (t < n_op8) { s = opf;  d = opb;  off = (size_t)t * 8; }
        else           { s = devf; d = devb; off = (size_t)(t - n_op8) * 8; }
        float4 x = *(const float4*)&s[off];
        float4 y = *(const float4*)&s[off + 4];
        u16x8 o;
        o[0] = bf16rn(x.x); o[1] = bf16rn(x.y); o[2] = bf16rn(x.z); o[3] = bf16rn(x.w);
        o[4] = bf16rn(y.x); o[5] = bf16rn(y.y); o[6] = bf16rn(y.z); o[7] = bf16rn(y.w);
        *(u16x8*)&d[off] = o;
        return;
    }
    t -= NU0;
    if (t < NU1) {
        int row = t >> 5, q = t & 31;
        float4 v;
        if (row < N_OP) v = *(const float4*)&opf[(size_t)row * 128 + q * 4];
        else            v = *(const float4*)&devf[(size_t)(row - N_OP) * 128 + q * 4];
        *(float4*)&out[(size_t)row * 256 + q * 4] = v;
        return;
    }
    t -= NU1;
    if (t < NU2) {
        if (t < 128 * 480) {   // wtop: segs prev, succ, serve
            int n = t / 480, kk = t % 480, seg = kk / 160, k = kk % 160;
            const float* Ws = (seg == 0) ? W1 : ((seg == 1) ? W2 : W4);
            const float* Bs = (seg == 0) ? B1 : ((seg == 1) ? B2 : B4);
            float v = (k < 144) ? Ws[(size_t)k * 128 + n] : ((k == 144) ? Bs[n] : 0.f);
            wtop[(size_t)n * 480 + kk] = bf16rn(v);
        } else {               // wtdev: segs link, place
            int q = t - 128 * 480;
            int n = q / 320, kk = q % 320, seg = kk / 160, k = kk % 160;
            const float* Ws = seg ? W3 : W0;
            const float* Bs = seg ? B3 : B0;
            float v = (k < 144) ? Ws[(size_t)k * 128 + n] : ((k == 144) ? Bs[n] : 0.f);
            wtdev[(size_t)n * 320 + kk] = bf16rn(v);
        }
        return;
    }
    t -= NU2;
    if (t >= ntot) return;
    const int* dp; int nb, eb;
    if (t < e1)      { dp = d0; nb = NB0; eb = 0; }
    else if (t < e2) { dp = d1; nb = NB1; eb = e1; }
    else if (t < e3) { dp = d2; nb = NB2; eb = e2; }
    else if (t < e4) { dp = d3; nb = NB3; eb = e3; }
    else             { dp = d4; nb = NB4; eb = e4; }
    atomicAdd(&deg[nb + dp[t - eb]], 1);
}

__global__ __launch_bounds__(256) void scan_block_kernel(
    const int* __restrict__ deg, int* __restrict__ starts,
    int* __restrict__ bsums, int n) {
    __shared__ int wsum[4];
    int tid = threadIdx.x;
    int base = blockIdx.x * 4096 + tid * 16;
    int v[16];
    int s = 0;
#pragma unroll
    for (int i = 0; i < 16; i++) {
        int idx = base + i;
        int t = (idx < n) ? deg[idx] : 0;
        v[i] = t; s += t;
    }
    int lane = tid & 63, wid = tid >> 6;
    int incl = s;
#pragma unroll
    for (int off = 1; off < 64; off <<= 1) {
        int t = __shfl_up(incl, off, 64);
        if (lane >= off) incl += t;
    }
    if (lane == 63) wsum[wid] = incl;
    __syncthreads();
    int woff = 0;
    for (int w2 = 0; w2 < wid; w2++) woff += wsum[w2];
    int run = woff + incl - s;
#pragma unroll
    for (int i = 0; i < 16; i++) {
        int idx = base + i;
        if (idx < n) starts[idx] = run;
        run += v[i];
    }
    if (tid == 255) bsums[blockIdx.x] = woff + incl;
}

__global__ void scan_bsums_kernel(int* __restrict__ bsums, int nb) {
    int lane = threadIdx.x;
    int v = (lane < nb) ? bsums[lane] : 0;
    int incl = v;
#pragma unroll
    for (int off = 1; off < 64; off <<= 1) {
        int t = __shfl_up(incl, off, 64);
        if (lane >= off) incl += t;
    }
    if (lane < nb) bsums[lane] = incl - v;
}

__global__ void scan_add_kernel(int* __restrict__ starts, int* __restrict__ scopy,
                                const int* __restrict__ bsums, int n) {
    int i = blockIdx.x * 256 + threadIdx.x;
    if (i < n) {
        int v = starts[i] + bsums[i >> 12];
        starts[i] = v;
        scopy[i] = v;
    }
}

__global__ void fill_all_kernel(const int* __restrict__ s0p, const int* __restrict__ s1p,
                                const int* __restrict__ s2p, const int* __restrict__ s3p,
                                const int* __restrict__ s4p,
                                const int* __restrict__ d0, const int* __restrict__ d1,
                                const int* __restrict__ d2, const int* __restrict__ d3,
                                const int* __restrict__ d4,
                                int e1, int e2, int e3, int e4, int ntot,
                                int* __restrict__ scopy, int2* __restrict__ edata) {
    int e = blockIdx.x * 256 + threadIdx.x;
    if (e >= ntot) return;
    const int* sp; const int* dp; int nb, eb;
    if (e < e1)      { sp = s0p; dp = d0; nb = NB0; eb = 0; }
    else if (e < e2) { sp = s1p; dp = d1; nb = NB1; eb = e1; }
    else if (e < e3) { sp = s2p; dp = d2; nb = NB2; eb = e2; }
    else if (e < e4) { sp = s3p; dp = d3; nb = NB3; eb = e3; }
    else             { sp = s4p; dp = d4; nb = NB4; eb = e4; }
    int el = e - eb;
    int g = nb + dp[el];
    int pos = atomicAdd(&scopy[g], 1);
    edata[pos] = make_int2(sp[el], el);
}

// One wave per dst node. 4 groups x 16 lanes; 4 edge chains in flight per
// group per iteration (16 edges/wave/iter). Lane gl holds dims gl*8..+7 as
// 4 (lo,hi) float2 pairs; ef dim gl. place-segment waves launched first.
__global__ __launch_bounds__(256) void agg_all_kernel(
    const u16* __restrict__ opb, const u16* __restrict__ devb,
    const float* __restrict__ ef0, const float* __restrict__ ef1,
    const float* __restrict__ ef2, const float* __restrict__ ef3,
    const float* __restrict__ ef4,
    const int2* __restrict__ edata, const int* __restrict__ starts,
    const int* __restrict__ deg, u16* __restrict__ agg) {
    int wl = (blockIdx.x * 256 + threadIdx.x) >> 6;
    // remap: place nodes [NB3,NB4) first (deg~120), then the rest in order
    int w = (wl < N_DEV) ? (NB3 + wl)
                         : ((wl - N_DEV < NB3) ? (wl - N_DEV) : wl);
    int lane = threadIdx.x & 63;
    int grp = lane >> 4, gl = lane & 15;
    const u16* sf; const float* efp;
    if (w < NB1)      { sf = devb; efp = ef0; }
    else if (w < NB2) { sf = opb;  efp = ef1; }
    else if (w < NB3) { sf = opb;  efp = ef2; }
    else if (w < NB4) { sf = opb;  efp = ef3; }
    else              { sf = devb; efp = ef4; }
    int s0 = starts[w], dg = deg[w];
    float2 a0 = {0.f, 0.f}, a1 = {0.f, 0.f}, a2 = {0.f, 0.f}, a3 = {0.f, 0.f};
    float aef = 0.f;
    for (int bb = 0; bb < dg; bb += 16) {
        int i0 = bb + grp;
        int2 e0 = make_int2(0, -1), e1 = make_int2(0, -1);
        int2 e2 = make_int2(0, -1), e3 = make_int2(0, -1);
        if (i0 < dg)      e0 = edata[s0 + i0];
        if (i0 + 4 < dg)  e1 = edata[s0 + i0 + 4];
        if (i0 + 8 < dg)  e2 = edata[s0 + i0 + 8];
        if (i0 + 12 < dg) e3 = edata[s0 + i0 + 12];
#define DOSLOT(ev)                                                            \
        if (ev.y >= 0) {                                                      \
            u32x4 f = *(const u32x4*)&sf[(size_t)ev.x * 128 + gl * 8];        \
            a0.x += __uint_as_float(f[0] << 16);                              \
            a0.y += __uint_as_float(f[0] & 0xffff0000u);                      \
            a1.x += __uint_as_float(f[1] << 16);                              \
            a1.y += __uint_as_float(f[1] & 0xffff0000u);                      \
            a2.x += __uint_as_float(f[2] << 16);                              \
            a2.y += __uint_as_float(f[2] & 0xffff0000u);                      \
            a3.x += __uint_as_float(f[3] << 16);                              \
            a3.y += __uint_as_float(f[3] & 0xffff0000u);                      \
            aef  += efp[(size_t)ev.y * 16 + gl];                              \
        }
        DOSLOT(e0) DOSLOT(e1) DOSLOT(e2) DOSLOT(e3)
#undef DOSLOT
    }
#define RED(x) x += __shfl_xor(x, 16); x += __shfl_xor(x, 32);
    RED(a0.x) RED(a0.y) RED(a1.x) RED(a1.y)
    RED(a2.x) RED(a2.y) RED(a3.x) RED(a3.y) RED(aef)
#undef RED
    float inv = (dg > 0) ? 1.f / (float)dg : 0.f;
    u16* row = &agg[(size_t)w * 160];
    if (lane < 16) {
        u16x8 o;
        o[0] = bf16rn(a0.x * inv); o[1] = bf16rn(a0.y * inv);
        o[2] = bf16rn(a1.x * inv); o[3] = bf16rn(a1.y * inv);
        o[4] = bf16rn(a2.x * inv); o[5] = bf16rn(a2.y * inv);
        o[6] = bf16rn(a3.x * inv); o[7] = bf16rn(a3.y * inv);
        *(u16x8*)&row[gl * 8] = o;
        row[128 + gl] = bf16rn(aef * inv);
    } else if (lane < 32) {
        int g2 = lane - 16;
        // k=144: degree mask (enables folded bias), 145..159: zero pad
        row[144 + g2] = (g2 == 0 && dg > 0) ? (u16)0x3F80 : (u16)0;
    }
}

// bf16 MFMA GEMM: block = 4 waves, 64 rows x 128 cols. Wave holds 16 rows,
// 8 col-tiles (acc f32x4 x8). A frags from aggb (row=lane&15, k-slice
// (lane>>4)*8); B frags from transposed Wt. Epilogue relu(acc*scale).
__global__ __launch_bounds__(256) void gemm_mfma_kernel(
    const u16* __restrict__ aggb, const u16* __restrict__ wtop,
    const u16* __restrict__ wtdev, float* __restrict__ out, int opblocks) {
    int bid = blockIdx.x, tid = threadIdx.x;
    int wave = tid >> 6, lane = tid & 63;
    bool isop = bid < opblocks;
    int rowbase, ndst, nseg, outrow0, Kpad, sb0, sb1, sb2;
    const u16* Wt; float scale;
    if (isop) {
        rowbase = bid * 64; ndst = N_OP; nseg = 3; outrow0 = 0;
        Kpad = 480; Wt = wtop; scale = 1.f / 3.f;
        sb0 = NB1; sb1 = NB2; sb2 = NB4;
    } else {
        rowbase = (bid - opblocks) * 64; ndst = N_DEV; nseg = 2; outrow0 = N_OP;
        Kpad = 320; Wt = wtdev; scale = 0.5f;
        sb0 = NB0; sb1 = NB3; sb2 = NB3;
    }
    int r16 = rowbase + wave * 16 + (lane & 15);
    int ar = min(r16, ndst - 1);
    int kq = (lane >> 4) * 8;
    f32x4 acc[8];
#pragma unroll
    for (int nt = 0; nt < 8; nt++) acc[nt] = (f32x4){0.f, 0.f, 0.f, 0.f};

    const u16* wbase = Wt + (size_t)(lane & 15) * Kpad + kq;
    for (int seg = 0; seg < nseg; seg++) {
        int segbase = (seg == 0) ? sb0 : ((seg == 1) ? sb1 : sb2);
        const u16* ap = aggb + (size_t)(segbase + ar) * 160 + kq;
        const u16* wp = wbase + seg * 160;
        for (int k0 = 0; k0 < 160; k0 += 32) {
            short8 a = *(const short8*)(ap + k0);
#pragma unroll
            for (int nt = 0; nt < 8; nt++) {
                short8 b = *(const short8*)(wp + (size_t)nt * 16 * Kpad + k0);
                acc[nt] = __builtin_amdgcn_mfma_f32_16x16x32_bf16(a, b, acc[nt], 0, 0, 0);
            }
        }
    }

    int colb = lane & 15;
    int rowe = rowbase + wave * 16 + (lane >> 4) * 4;
#pragma unroll
    for (int nt = 0; nt < 8; nt++) {
#pragma unroll
        for (int r = 0; r < 4; r++) {
            int row = rowe + r;
            if (row < ndst)
                out[(size_t)(outrow0 + row) * 256 + 128 + nt * 16 + colb] =
                    fmaxf(acc[nt][r] * scale, 0.f);
        }
    }
}

extern "C" void kernel_launch(void* const* d_in, const int* in_sizes, int n_in,
                              void* d_out, int out_size, void* d_ws, size_t ws_size,
                              hipStream_t stream) {
    const float* opf  = (const float*)d_in[0];
    const float* devf = (const float*)d_in[1];
    const float* ef[5]; const int* src[5]; const int* dst[5];
    const float* W[5]; const float* bias[5];
    int ne[5];
    for (int i = 0; i < 5; i++) {
        ef[i]   = (const float*)d_in[2 + 5 * i + 0];
        src[i]  = (const int*)  d_in[2 + 5 * i + 1];
        dst[i]  = (const int*)  d_in[2 + 5 * i + 2];
        W[i]    = (const float*)d_in[2 + 5 * i + 3];
        bias[i] = (const float*)d_in[2 + 5 * i + 4];
        ne[i]   = in_sizes[2 + 5 * i + 1];
    }
    int e1 = ne[0], e2 = e1 + ne[1], e3 = e2 + ne[2], e4 = e3 + ne[3];
    int ntot = e4 + ne[4];
    int ntot_pad = (ntot + 1) & ~1;

    char* wp = (char*)d_ws;
    int* deg    = (int*)wp;  wp += (size_t)N_NODES * 4;
    int* starts = (int*)wp;  wp += (size_t)N_NODES * 4;
    int* scopy  = (int*)wp;  wp += (size_t)N_NODES * 4;
    int* bsums  = (int*)wp;  wp += 256;
    int2* edata = (int2*)wp; wp += (size_t)ntot_pad * 8;
    u16* aggb   = (u16*)wp;  wp += (size_t)N_NODES * 160 * 2;
    u16* opb    = (u16*)wp;  wp += (size_t)N_OP * 128 * 2;
    u16* devb   = (u16*)wp;  wp += (size_t)N_DEV * 128 * 2;
    u16* wtop   = (u16*)wp;  wp += (size_t)128 * 480 * 2;
    u16* wtdev  = (u16*)wp;
    float* out  = (float*)d_out;

    zero_int_kernel<<<(N_NODES + 255) / 256, 256, 0, stream>>>(deg, N_NODES);

    const int NU = (N_OP + N_DEV) * 48 + 128 * 800;  // conv+copy+wt units
    prep_kernel<<<(NU + ntot + 255) / 256, 256, 0, stream>>>(
        opf, devf, W[0], W[1], W[2], W[3], W[4],
        bias[0], bias[1], bias[2], bias[3], bias[4],
        dst[0], dst[1], dst[2], dst[3], dst[4],
        e1, e2, e3, e4, ntot, opb, devb, out, wtop, wtdev, deg);

    const int nchunks = (N_NODES + 4095) / 4096;  // 40
    scan_block_kernel<<<nchunks, 256, 0, stream>>>(deg, starts, bsums, N_NODES);
    scan_bsums_kernel<<<1, 64, 0, stream>>>(bsums, nchunks);
    scan_add_kernel<<<(N_NODES + 255) / 256, 256, 0, stream>>>(starts, scopy, bsums, N_NODES);

    fill_all_kernel<<<(ntot + 255) / 256, 256, 0, stream>>>(
        src[0], src[1], src[2], src[3], src[4],
        dst[0], dst[1], dst[2], dst[3], dst[4],
        e1, e2, e3, e4, ntot, scopy, edata);

    agg_all_kernel<<<N_NODES / 4, 256, 0, stream>>>(
        opb, devb, ef[0], ef[1], ef[2], ef[3], ef[4], edata, starts, deg, aggb);

    int opblocks = (N_OP + 63) / 64, devblocks = (N_DEV + 63) / 64;
    gemm_mfma_kernel<<<opblocks + devblocks, 256, 0, stream>>>(
        aggb, wtop, wtdev, out, opblocks);
    (void)n_in; (void)out_size; (void)ws_size;
}

// Round 4
// 422.238 us; speedup vs baseline: 1.9565x; 1.1583x over previous
//
#include <hip/hip_runtime.h>

// ---------------------------------------------------------------------------
// GConv via  mean_e(concat(x_src, ef) @ W + b) = mean_feats @ W + mask*b
// zero -> prep(conv bf16 + copy left + Wt build + degree count) ->
// scan(3, cursor init folded) -> two-phase bucket sort (binA runs, binB
// exact positions in LDS) -> agg (4-chain ILP, bf16 means, mask in K-pad)
// -> bf16 MFMA GEMM (op K=480, dev K=320), bias folded into K=144 slot.
// ---------------------------------------------------------------------------

#define N_OP    50000
#define N_DEV   5000
#define N_NODES 160000
#define NB0 0
#define NB1 5000
#define NB2 55000
#define NB3 105000
#define NB4 110000

#define NBUCK   5000     // 32 nodes per bucket
#define BSHIFT  5
#define CHUNK   8192     // edges per binA block
#define STAGE_CAP 5120   // max records per bucket (place worst ~4.1k)

typedef unsigned short u16;
typedef unsigned int   u32;
typedef __attribute__((ext_vector_type(8))) unsigned short u16x8;
typedef __attribute__((ext_vector_type(4))) unsigned int   u32x4;
typedef __attribute__((ext_vector_type(8))) short          short8;
typedef __attribute__((ext_vector_type(4))) float          f32x4;

__device__ __forceinline__ u16 bf16rn(float x) {
    unsigned u = __float_as_uint(x);
    return (u16)((u + 0x7fffu + ((u >> 16) & 1u)) >> 16);
}

__global__ void zero_int_kernel(int* __restrict__ p, int n) {
    int i = blockIdx.x * 256 + threadIdx.x;
    if (i < n) p[i] = 0;
}

// Fused: feats->bf16, copy left half of out, build Wt (bf16, transposed,
// bias folded at k=144), degree count.
__global__ __launch_bounds__(256) void prep_kernel(
    const float* __restrict__ opf, const float* __restrict__ devf,
    const float* __restrict__ W0, const float* __restrict__ W1,
    const float* __restrict__ W2, const float* __restrict__ W3,
    const float* __restrict__ W4,
    const float* __restrict__ B0, const float* __restrict__ B1,
    const float* __restrict__ B2, const float* __restrict__ B3,
    const float* __restrict__ B4,
    const int* __restrict__ d0, const int* __restrict__ d1,
    const int* __restrict__ d2, const int* __restrict__ d3,
    const int* __restrict__ d4,
    int e1, int e2, int e3, int e4, int ntot,
    u16* __restrict__ opb, u16* __restrict__ devb,
    float* __restrict__ out, u16* __restrict__ wtop, u16* __restrict__ wtdev,
    int* __restrict__ deg) {
    const int NU0 = (N_OP + N_DEV) * 16;   // conv units (8 elems)
    const int NU1 = (N_OP + N_DEV) * 32;   // copy units (float4)
    const int NU2 = 128 * 480 + 128 * 320; // wt elems
    int t = blockIdx.x * 256 + threadIdx.x;
    if (t < NU0) {
        const int n_op8 = N_OP * 16;
        const float* s; u16* d; size_t off;
        if (t < n_op8) { s = opf;  d = opb;  off = (size_t)t * 8; }
        else           { s = devf; d = devb; off = (size_t)(t - n_op8) * 8; }
        float4 x = *(const float4*)&s[off];
        float4 y = *(const float4*)&s[off + 4];
        u16x8 o;
        o[0] = bf16rn(x.x); o[1] = bf16rn(x.y); o[2] = bf16rn(x.z); o[3] = bf16rn(x.w);
        o[4] = bf16rn(y.x); o[5] = bf16rn(y.y); o[6] = bf16rn(y.z); o[7] = bf16rn(y.w);
        *(u16x8*)&d[off] = o;
        return;
    }
    t -= NU0;
    if (t < NU1) {
        int row = t >> 5, q = t & 31;
        float4 v;
        if (row < N_OP) v = *(const float4*)&opf[(size_t)row * 128 + q * 4];
        else            v = *(const float4*)&devf[(size_t)(row - N_OP) * 128 + q * 4];
        *(float4*)&out[(size_t)row * 256 + q * 4] = v;
        return;
    }
    t -= NU1;
    if (t < NU2) {
        if (t < 128 * 480) {   // wtop: segs prev, succ, serve
            int n = t / 480, kk = t % 480, seg = kk / 160, k = kk % 160;
            const float* Ws = (seg == 0) ? W1 : ((seg == 1) ? W2 : W4);
            const float* Bs = (seg == 0) ? B1 : ((seg == 1) ? B2 : B4);
            float v = (k < 144) ? Ws[(size_t)k * 128 + n] : ((k == 144) ? Bs[n] : 0.f);
            wtop[(size_t)n * 480 + kk] = bf16rn(v);
        } else {               // wtdev: segs link, place
            int q = t - 128 * 480;
            int n = q / 320, kk = q % 320, seg = kk / 160, k = kk % 160;
            const float* Ws = seg ? W3 : W0;
            const float* Bs = seg ? B3 : B0;
            float v = (k < 144) ? Ws[(size_t)k * 128 + n] : ((k == 144) ? Bs[n] : 0.f);
            wtdev[(size_t)n * 320 + kk] = bf16rn(v);
        }
        return;
    }
    t -= NU2;
    if (t >= ntot) return;
    const int* dp; int nb, eb;
    if (t < e1)      { dp = d0; nb = NB0; eb = 0; }
    else if (t < e2) { dp = d1; nb = NB1; eb = e1; }
    else if (t < e3) { dp = d2; nb = NB2; eb = e2; }
    else if (t < e4) { dp = d3; nb = NB3; eb = e3; }
    else             { dp = d4; nb = NB4; eb = e4; }
    atomicAdd(&deg[nb + dp[t - eb]], 1);
}

__global__ __launch_bounds__(256) void scan_block_kernel(
    const int* __restrict__ deg, int* __restrict__ starts,
    int* __restrict__ bsums, int n) {
    __shared__ int wsum[4];
    int tid = threadIdx.x;
    int base = blockIdx.x * 4096 + tid * 16;
    int v[16];
    int s = 0;
#pragma unroll
    for (int i = 0; i < 16; i++) {
        int idx = base + i;
        int t = (idx < n) ? deg[idx] : 0;
        v[i] = t; s += t;
    }
    int lane = tid & 63, wid = tid >> 6;
    int incl = s;
#pragma unroll
    for (int off = 1; off < 64; off <<= 1) {
        int t = __shfl_up(incl, off, 64);
        if (lane >= off) incl += t;
    }
    if (lane == 63) wsum[wid] = incl;
    __syncthreads();
    int woff = 0;
    for (int w2 = 0; w2 < wid; w2++) woff += wsum[w2];
    int run = woff + incl - s;
#pragma unroll
    for (int i = 0; i < 16; i++) {
        int idx = base + i;
        if (idx < n) starts[idx] = run;
        run += v[i];
    }
    if (tid == 255) bsums[blockIdx.x] = woff + incl;
}

__global__ void scan_bsums_kernel(int* __restrict__ bsums, int nb) {
    int lane = threadIdx.x;
    int v = (lane < nb) ? bsums[lane] : 0;
    int incl = v;
#pragma unroll
    for (int off = 1; off < 64; off <<= 1) {
        int t = __shfl_up(incl, off, 64);
        if (lane >= off) incl += t;
    }
    if (lane < nb) bsums[lane] = incl - v;
}

__global__ void scan_add_kernel(int* __restrict__ starts, int* __restrict__ cursor,
                                const int* __restrict__ bsums, int n) {
    int i = blockIdx.x * 256 + threadIdx.x;
    if (i < n) {
        int v = starts[i] + bsums[i >> 12];
        starts[i] = v;
        if ((i & 31) == 0) cursor[i >> BSHIFT] = v;   // bucket base
    }
}

// Phase A: bin edges into 32-node buckets; records land inside the bucket's
// final CSR region (arbitrary order within bucket). Record packs
// (src | nodeLocal<<16, edge_local). One global atomic per (block,bucket).
__global__ __launch_bounds__(256) void binA_kernel(
    const int* __restrict__ s0p, const int* __restrict__ s1p,
    const int* __restrict__ s2p, const int* __restrict__ s3p,
    const int* __restrict__ s4p,
    const int* __restrict__ d0, const int* __restrict__ d1,
    const int* __restrict__ d2, const int* __restrict__ d3,
    const int* __restrict__ d4,
    int e1, int e2, int e3, int e4, int ntot,
    int* __restrict__ cursor, int2* __restrict__ edata) {
    __shared__ int cnt[NBUCK];
    __shared__ int base[NBUCK];
    int tid = threadIdx.x;
    int e0 = blockIdx.x * CHUNK;
    for (int i = tid; i < NBUCK; i += 256) cnt[i] = 0;
    __syncthreads();
    int myg[32];
#pragma unroll 4
    for (int j = 0; j < 32; j++) {
        int e = e0 + j * 256 + tid;
        int g = -1;
        if (e < ntot) {
            const int* dp; int nb, eb;
            if (e < e1)      { dp = d0; nb = NB0; eb = 0; }
            else if (e < e2) { dp = d1; nb = NB1; eb = e1; }
            else if (e < e3) { dp = d2; nb = NB2; eb = e2; }
            else if (e < e4) { dp = d3; nb = NB3; eb = e3; }
            else             { dp = d4; nb = NB4; eb = e4; }
            g = nb + dp[e - eb];
            atomicAdd(&cnt[g >> BSHIFT], 1);
        }
        myg[j] = g;
    }
    __syncthreads();
    for (int b = tid; b < NBUCK; b += 256) {
        int c = cnt[b];
        base[b] = c ? atomicAdd(&cursor[b], c) : 0;
    }
    __syncthreads();
#pragma unroll 4
    for (int j = 0; j < 32; j++) {
        int g = myg[j];
        if (g < 0) continue;
        int e = e0 + j * 256 + tid;
        const int* sp; int eb;
        if (e < e1)      { sp = s0p; eb = 0; }
        else if (e < e2) { sp = s1p; eb = e1; }
        else if (e < e3) { sp = s2p; eb = e2; }
        else if (e < e4) { sp = s3p; eb = e3; }
        else             { sp = s4p; eb = e4; }
        int el = e - eb;
        int b = g >> BSHIFT;
        int pos = base[b] + atomicSub(&cnt[b], 1) - 1;
        edata[pos] = make_int2(sp[el] | ((g & 31) << 16), el);
    }
}

// Phase B: per-bucket exact placement. Read bucket region, scatter to exact
// per-node ranks in LDS, write back coalesced (strips node bits).
__global__ __launch_bounds__(256) void binB_kernel(
    const int* __restrict__ starts, int ntot, int2* __restrict__ edata) {
    __shared__ int ncur[32];
    __shared__ int2 stage[STAGE_CAP];
    int b = blockIdx.x, tid = threadIdx.x;
    int n0 = b << BSHIFT;
    int bstart = starts[n0];
    int bend = (b == NBUCK - 1) ? ntot : starts[n0 + 32];
    int cnt = bend - bstart;
    if (tid < 32) ncur[tid] = starts[n0 + tid] - bstart;
    __syncthreads();
    for (int i = tid; i < cnt; i += 256) {
        int2 r = edata[bstart + i];
        int l = (r.x >> 16) & 31;
        int rank = atomicAdd(&ncur[l], 1);
        stage[rank] = make_int2(r.x & 0xffff, r.y);
    }
    __syncthreads();
    for (int i = tid; i < cnt; i += 256)
        edata[bstart + i] = stage[i];
}

// One wave per dst node. 4 groups x 16 lanes; 4 edge chains in flight per
// group per iteration (16 edges/wave/iter). Lane gl holds dims gl*8..+7 as
// 4 (lo,hi) float2 pairs; ef dim gl. place-segment waves launched first.
__global__ __launch_bounds__(256) void agg_all_kernel(
    const u16* __restrict__ opb, const u16* __restrict__ devb,
    const float* __restrict__ ef0, const float* __restrict__ ef1,
    const float* __restrict__ ef2, const float* __restrict__ ef3,
    const float* __restrict__ ef4,
    const int2* __restrict__ edata, const int* __restrict__ starts,
    const int* __restrict__ deg, u16* __restrict__ agg) {
    int wl = (blockIdx.x * 256 + threadIdx.x) >> 6;
    int w = (wl < N_DEV) ? (NB3 + wl)
                         : ((wl - N_DEV < NB3) ? (wl - N_DEV) : wl);
    int lane = threadIdx.x & 63;
    int grp = lane >> 4, gl = lane & 15;
    const u16* sf; const float* efp;
    if (w < NB1)      { sf = devb; efp = ef0; }
    else if (w < NB2) { sf = opb;  efp = ef1; }
    else if (w < NB3) { sf = opb;  efp = ef2; }
    else if (w < NB4) { sf = opb;  efp = ef3; }
    else              { sf = devb; efp = ef4; }
    int s0 = starts[w], dg = deg[w];
    float2 a0 = {0.f, 0.f}, a1 = {0.f, 0.f}, a2 = {0.f, 0.f}, a3 = {0.f, 0.f};
    float aef = 0.f;
    for (int bb = 0; bb < dg; bb += 16) {
        int i0 = bb + grp;
        int2 e0 = make_int2(0, -1), e1 = make_int2(0, -1);
        int2 e2 = make_int2(0, -1), e3 = make_int2(0, -1);
        if (i0 < dg)      e0 = edata[s0 + i0];
        if (i0 + 4 < dg)  e1 = edata[s0 + i0 + 4];
        if (i0 + 8 < dg)  e2 = edata[s0 + i0 + 8];
        if (i0 + 12 < dg) e3 = edata[s0 + i0 + 12];
#define DOSLOT(ev)                                                            \
        if (ev.y >= 0) {                                                      \
            u32x4 f = *(const u32x4*)&sf[(size_t)ev.x * 128 + gl * 8];        \
            a0.x += __uint_as_float(f[0] << 16);                              \
            a0.y += __uint_as_float(f[0] & 0xffff0000u);                      \
            a1.x += __uint_as_float(f[1] << 16);                              \
            a1.y += __uint_as_float(f[1] & 0xffff0000u);                      \
            a2.x += __uint_as_float(f[2] << 16);                              \
            a2.y += __uint_as_float(f[2] & 0xffff0000u);                      \
            a3.x += __uint_as_float(f[3] << 16);                              \
            a3.y += __uint_as_float(f[3] & 0xffff0000u);                      \
            aef  += efp[(size_t)ev.y * 16 + gl];                              \
        }
        DOSLOT(e0) DOSLOT(e1) DOSLOT(e2) DOSLOT(e3)
#undef DOSLOT
    }
#define RED(x) x += __shfl_xor(x, 16); x += __shfl_xor(x, 32);
    RED(a0.x) RED(a0.y) RED(a1.x) RED(a1.y)
    RED(a2.x) RED(a2.y) RED(a3.x) RED(a3.y) RED(aef)
#undef RED
    float inv = (dg > 0) ? 1.f / (float)dg : 0.f;
    u16* row = &agg[(size_t)w * 160];
    if (lane < 16) {
        u16x8 o;
        o[0] = bf16rn(a0.x * inv); o[1] = bf16rn(a0.y * inv);
        o[2] = bf16rn(a1.x * inv); o[3] = bf16rn(a1.y * inv);
        o[4] = bf16rn(a2.x * inv); o[5] = bf16rn(a2.y * inv);
        o[6] = bf16rn(a3.x * inv); o[7] = bf16rn(a3.y * inv);
        *(u16x8*)&row[gl * 8] = o;
        row[128 + gl] = bf16rn(aef * inv);
    } else if (lane < 32) {
        int g2 = lane - 16;
        row[144 + g2] = (g2 == 0 && dg > 0) ? (u16)0x3F80 : (u16)0;
    }
}

// bf16 MFMA GEMM: block = 4 waves, 64 rows x 128 cols. Wave holds 16 rows,
// 8 col-tiles (acc f32x4 x8). Epilogue relu(acc*scale); bias via K=144 slot.
__global__ __launch_bounds__(256) void gemm_mfma_kernel(
    const u16* __restrict__ aggb, const u16* __restrict__ wtop,
    const u16* __restrict__ wtdev, float* __restrict__ out, int opblocks) {
    int bid = blockIdx.x, tid = threadIdx.x;
    int wave = tid >> 6, lane = tid & 63;
    bool isop = bid < opblocks;
    int rowbase, ndst, nseg, outrow0, Kpad, sb0, sb1, sb2;
    const u16* Wt; float scale;
    if (isop) {
        rowbase = bid * 64; ndst = N_OP; nseg = 3; outrow0 = 0;
        Kpad = 480; Wt = wtop; scale = 1.f / 3.f;
        sb0 = NB1; sb1 = NB2; sb2 = NB4;
    } else {
        rowbase = (bid - opblocks) * 64; ndst = N_DEV; nseg = 2; outrow0 = N_OP;
        Kpad = 320; Wt = wtdev; scale = 0.5f;
        sb0 = NB0; sb1 = NB3; sb2 = NB3;
    }
    int r16 = rowbase + wave * 16 + (lane & 15);
    int ar = min(r16, ndst - 1);
    int kq = (lane >> 4) * 8;
    f32x4 acc[8];
#pragma unroll
    for (int nt = 0; nt < 8; nt++) acc[nt] = (f32x4){0.f, 0.f, 0.f, 0.f};

    const u16* wbase = Wt + (size_t)(lane & 15) * Kpad + kq;
    for (int seg = 0; seg < nseg; seg++) {
        int segbase = (seg == 0) ? sb0 : ((seg == 1) ? sb1 : sb2);
        const u16* ap = aggb + (size_t)(segbase + ar) * 160 + kq;
        const u16* wp = wbase + seg * 160;
        for (int k0 = 0; k0 < 160; k0 += 32) {
            short8 a = *(const short8*)(ap + k0);
#pragma unroll
            for (int nt = 0; nt < 8; nt++) {
                short8 b = *(const short8*)(wp + (size_t)nt * 16 * Kpad + k0);
                acc[nt] = __builtin_amdgcn_mfma_f32_16x16x32_bf16(a, b, acc[nt], 0, 0, 0);
            }
        }
    }

    int colb = lane & 15;
    int rowe = rowbase + wave * 16 + (lane >> 4) * 4;
#pragma unroll
    for (int nt = 0; nt < 8; nt++) {
#pragma unroll
        for (int r = 0; r < 4; r++) {
            int row = rowe + r;
            if (row < ndst)
                out[(size_t)(outrow0 + row) * 256 + 128 + nt * 16 + colb] =
                    fmaxf(acc[nt][r] * scale, 0.f);
        }
    }
}

extern "C" void kernel_launch(void* const* d_in, const int* in_sizes, int n_in,
                              void* d_out, int out_size, void* d_ws, size_t ws_size,
                              hipStream_t stream) {
    const float* opf  = (const float*)d_in[0];
    const float* devf = (const float*)d_in[1];
    const float* ef[5]; const int* src[5]; const int* dst[5];
    const float* W[5]; const float* bias[5];
    int ne[5];
    for (int i = 0; i < 5; i++) {
        ef[i]   = (const float*)d_in[2 + 5 * i + 0];
        src[i]  = (const int*)  d_in[2 + 5 * i + 1];
        dst[i]  = (const int*)  d_in[2 + 5 * i + 2];
        W[i]    = (const float*)d_in[2 + 5 * i + 3];
        bias[i] = (const float*)d_in[2 + 5 * i + 4];
        ne[i]   = in_sizes[2 + 5 * i + 1];
    }
    int e1 = ne[0], e2 = e1 + ne[1], e3 = e2 + ne[2], e4 = e3 + ne[3];
    int ntot = e4 + ne[4];
    int ntot_pad = (ntot + 1) & ~1;

    char* wp = (char*)d_ws;
    int* deg    = (int*)wp;  wp += (size_t)N_NODES * 4;
    int* starts = (int*)wp;  wp += (size_t)N_NODES * 4;
    int* cursor = (int*)wp;  wp += (size_t)NBUCK * 4;
    int* bsums  = (int*)wp;  wp += 256;
    int2* edata = (int2*)wp; wp += (size_t)ntot_pad * 8;
    u16* aggb   = (u16*)wp;  wp += (size_t)N_NODES * 160 * 2;
    u16* opb    = (u16*)wp;  wp += (size_t)N_OP * 128 * 2;
    u16* devb   = (u16*)wp;  wp += (size_t)N_DEV * 128 * 2;
    u16* wtop   = (u16*)wp;  wp += (size_t)128 * 480 * 2;
    u16* wtdev  = (u16*)wp;
    float* out  = (float*)d_out;

    zero_int_kernel<<<(N_NODES + 255) / 256, 256, 0, stream>>>(deg, N_NODES);

    const int NU = (N_OP + N_DEV) * 48 + 128 * 800;  // conv+copy+wt units
    prep_kernel<<<(NU + ntot + 255) / 256, 256, 0, stream>>>(
        opf, devf, W[0], W[1], W[2], W[3], W[4],
        bias[0], bias[1], bias[2], bias[3], bias[4],
        dst[0], dst[1], dst[2], dst[3], dst[4],
        e1, e2, e3, e4, ntot, opb, devb, out, wtop, wtdev, deg);

    const int nchunks = (N_NODES + 4095) / 4096;  // 40
    scan_block_kernel<<<nchunks, 256, 0, stream>>>(deg, starts, bsums, N_NODES);
    scan_bsums_kernel<<<1, 64, 0, stream>>>(bsums, nchunks);
    scan_add_kernel<<<(N_NODES + 255) / 256, 256, 0, stream>>>(starts, cursor, bsums, N_NODES);

    binA_kernel<<<(ntot + CHUNK - 1) / CHUNK, 256, 0, stream>>>(
        src[0], src[1], src[2], src[3], src[4],
        dst[0], dst[1], dst[2], dst[3], dst[4],
        e1, e2, e3, e4, ntot, cursor, edata);

    binB_kernel<<<NBUCK, 256, 0, stream>>>(starts, ntot, edata);

    agg_all_kernel<<<N_NODES / 4, 256, 0, stream>>>(
        opb, devb, ef[0], ef[1], ef[2], ef[3], ef[4], edata, starts, deg, aggb);

    int opblocks = (N_OP + 63) / 64, devblocks = (N_DEV + 63) / 64;
    gemm_mfma_kernel<<<opblocks + devblocks, 256, 0, stream>>>(
        aggb, wtop, wtdev, out, opblocks);
    (void)n_in; (void)out_size; (void)ws_size;
}

// Round 5
// 408.332 us; speedup vs baseline: 2.0232x; 1.0341x over previous
//
#include <hip/hip_runtime.h>

// ---------------------------------------------------------------------------
// GConv via  mean_e(concat(x_src, ef) @ W + b) = mean_feats @ W + mask*b
// zero -> prep(conv bf16 + copy left + Wt build + degree count) ->
// scan(3, cursor init folded) -> two-phase bucket sort (binA runs, binB
// exact positions in LDS) -> agg (8-chain ILP, nt streams, bf16 means) ->
// bf16 MFMA GEMM (op K=480, dev K=320), bias folded into K=144 slot.
// ---------------------------------------------------------------------------

#define N_OP    50000
#define N_DEV   5000
#define N_NODES 160000
#define NB0 0
#define NB1 5000
#define NB2 55000
#define NB3 105000
#define NB4 110000

#define NBUCK   5000     // 32 nodes per bucket
#define BSHIFT  5
#define CHUNK   8192     // edges per binA block
#define STAGE_CAP 5120   // max records per bucket (place worst ~4.1k)

typedef unsigned short u16;
typedef unsigned int   u32;
typedef __attribute__((ext_vector_type(8))) unsigned short u16x8;
typedef __attribute__((ext_vector_type(4))) unsigned int   u32x4;
typedef __attribute__((ext_vector_type(8))) short          short8;
typedef __attribute__((ext_vector_type(4))) float          f32x4;

__device__ __forceinline__ u16 bf16rn(float x) {
    unsigned u = __float_as_uint(x);
    return (u16)((u + 0x7fffu + ((u >> 16) & 1u)) >> 16);
}

__global__ void zero_int_kernel(int* __restrict__ p, int n) {
    int i = blockIdx.x * 256 + threadIdx.x;
    if (i < n) p[i] = 0;
}

// Fused: feats->bf16, copy left half of out, build Wt (bf16, transposed,
// bias folded at k=144), degree count.
__global__ __launch_bounds__(256) void prep_kernel(
    const float* __restrict__ opf, const float* __restrict__ devf,
    const float* __restrict__ W0, const float* __restrict__ W1,
    const float* __restrict__ W2, const float* __restrict__ W3,
    const float* __restrict__ W4,
    const float* __restrict__ B0, const float* __restrict__ B1,
    const float* __restrict__ B2, const float* __restrict__ B3,
    const float* __restrict__ B4,
    const int* __restrict__ d0, const int* __restrict__ d1,
    const int* __restrict__ d2, const int* __restrict__ d3,
    const int* __restrict__ d4,
    int e1, int e2, int e3, int e4, int ntot,
    u16* __restrict__ opb, u16* __restrict__ devb,
    float* __restrict__ out, u16* __restrict__ wtop, u16* __restrict__ wtdev,
    int* __restrict__ deg) {
    const int NU0 = (N_OP + N_DEV) * 16;   // conv units (8 elems)
    const int NU1 = (N_OP + N_DEV) * 32;   // copy units (float4)
    const int NU2 = 128 * 480 + 128 * 320; // wt elems
    int t = blockIdx.x * 256 + threadIdx.x;
    if (t < NU0) {
        const int n_op8 = N_OP * 16;
        const float* s; u16* d; size_t off;
        if (t < n_op8) { s = opf;  d = opb;  off = (size_t)t * 8; }
        else           { s = devf; d = devb; off = (size_t)(t - n_op8) * 8; }
        float4 x = *(const float4*)&s[off];
        float4 y = *(const float4*)&s[off + 4];
        u16x8 o;
        o[0] = bf16rn(x.x); o[1] = bf16rn(x.y); o[2] = bf16rn(x.z); o[3] = bf16rn(x.w);
        o[4] = bf16rn(y.x); o[5] = bf16rn(y.y); o[6] = bf16rn(y.z); o[7] = bf16rn(y.w);
        *(u16x8*)&d[off] = o;
        return;
    }
    t -= NU0;
    if (t < NU1) {
        int row = t >> 5, q = t & 31;
        float4 v;
        if (row < N_OP) v = *(const float4*)&opf[(size_t)row * 128 + q * 4];
        else            v = *(const float4*)&devf[(size_t)(row - N_OP) * 128 + q * 4];
        *(float4*)&out[(size_t)row * 256 + q * 4] = v;
        return;
    }
    t -= NU1;
    if (t < NU2) {
        if (t < 128 * 480) {   // wtop: segs prev, succ, serve
            int n = t / 480, kk = t % 480, seg = kk / 160, k = kk % 160;
            const float* Ws = (seg == 0) ? W1 : ((seg == 1) ? W2 : W4);
            const float* Bs = (seg == 0) ? B1 : ((seg == 1) ? B2 : B4);
            float v = (k < 144) ? Ws[(size_t)k * 128 + n] : ((k == 144) ? Bs[n] : 0.f);
            wtop[(size_t)n * 480 + kk] = bf16rn(v);
        } else {               // wtdev: segs link, place
            int q = t - 128 * 480;
            int n = q / 320, kk = q % 320, seg = kk / 160, k = kk % 160;
            const float* Ws = seg ? W3 : W0;
            const float* Bs = seg ? B3 : B0;
            float v = (k < 144) ? Ws[(size_t)k * 128 + n] : ((k == 144) ? Bs[n] : 0.f);
            wtdev[(size_t)n * 320 + kk] = bf16rn(v);
        }
        return;
    }
    t -= NU2;
    if (t >= ntot) return;
    const int* dp; int nb, eb;
    if (t < e1)      { dp = d0; nb = NB0; eb = 0; }
    else if (t < e2) { dp = d1; nb = NB1; eb = e1; }
    else if (t < e3) { dp = d2; nb = NB2; eb = e2; }
    else if (t < e4) { dp = d3; nb = NB3; eb = e3; }
    else             { dp = d4; nb = NB4; eb = e4; }
    atomicAdd(&deg[nb + dp[t - eb]], 1);
}

__global__ __launch_bounds__(256) void scan_block_kernel(
    const int* __restrict__ deg, int* __restrict__ starts,
    int* __restrict__ bsums, int n) {
    __shared__ int wsum[4];
    int tid = threadIdx.x;
    int base = blockIdx.x * 4096 + tid * 16;
    int v[16];
    int s = 0;
#pragma unroll
    for (int i = 0; i < 16; i++) {
        int idx = base + i;
        int t = (idx < n) ? deg[idx] : 0;
        v[i] = t; s += t;
    }
    int lane = tid & 63, wid = tid >> 6;
    int incl = s;
#pragma unroll
    for (int off = 1; off < 64; off <<= 1) {
        int t = __shfl_up(incl, off, 64);
        if (lane >= off) incl += t;
    }
    if (lane == 63) wsum[wid] = incl;
    __syncthreads();
    int woff = 0;
    for (int w2 = 0; w2 < wid; w2++) woff += wsum[w2];
    int run = woff + incl - s;
#pragma unroll
    for (int i = 0; i < 16; i++) {
        int idx = base + i;
        if (idx < n) starts[idx] = run;
        run += v[i];
    }
    if (tid == 255) bsums[blockIdx.x] = woff + incl;
}

__global__ void scan_bsums_kernel(int* __restrict__ bsums, int nb) {
    int lane = threadIdx.x;
    int v = (lane < nb) ? bsums[lane] : 0;
    int incl = v;
#pragma unroll
    for (int off = 1; off < 64; off <<= 1) {
        int t = __shfl_up(incl, off, 64);
        if (lane >= off) incl += t;
    }
    if (lane < nb) bsums[lane] = incl - v;
}

__global__ void scan_add_kernel(int* __restrict__ starts, int* __restrict__ cursor,
                                const int* __restrict__ bsums, int n) {
    int i = blockIdx.x * 256 + threadIdx.x;
    if (i < n) {
        int v = starts[i] + bsums[i >> 12];
        starts[i] = v;
        if ((i & 31) == 0) cursor[i >> BSHIFT] = v;   // bucket base
    }
}

// Phase A: bin edges into 32-node buckets; records land inside the bucket's
// final CSR region (arbitrary order within bucket). Record packs
// (src | nodeLocal<<16, edge_local). One global atomic per (block,bucket).
__global__ __launch_bounds__(256) void binA_kernel(
    const int* __restrict__ s0p, const int* __restrict__ s1p,
    const int* __restrict__ s2p, const int* __restrict__ s3p,
    const int* __restrict__ s4p,
    const int* __restrict__ d0, const int* __restrict__ d1,
    const int* __restrict__ d2, const int* __restrict__ d3,
    const int* __restrict__ d4,
    int e1, int e2, int e3, int e4, int ntot,
    int* __restrict__ cursor, int2* __restrict__ edata) {
    __shared__ int cnt[NBUCK];
    __shared__ int base[NBUCK];
    int tid = threadIdx.x;
    int e0 = blockIdx.x * CHUNK;
    for (int i = tid; i < NBUCK; i += 256) cnt[i] = 0;
    __syncthreads();
    int myg[32];
#pragma unroll 4
    for (int j = 0; j < 32; j++) {
        int e = e0 + j * 256 + tid;
        int g = -1;
        if (e < ntot) {
            const int* dp; int nb, eb;
            if (e < e1)      { dp = d0; nb = NB0; eb = 0; }
            else if (e < e2) { dp = d1; nb = NB1; eb = e1; }
            else if (e < e3) { dp = d2; nb = NB2; eb = e2; }
            else if (e < e4) { dp = d3; nb = NB3; eb = e3; }
            else             { dp = d4; nb = NB4; eb = e4; }
            g = nb + dp[e - eb];
            atomicAdd(&cnt[g >> BSHIFT], 1);
        }
        myg[j] = g;
    }
    __syncthreads();
    for (int b = tid; b < NBUCK; b += 256) {
        int c = cnt[b];
        base[b] = c ? atomicAdd(&cursor[b], c) : 0;
    }
    __syncthreads();
#pragma unroll 4
    for (int j = 0; j < 32; j++) {
        int g = myg[j];
        if (g < 0) continue;
        int e = e0 + j * 256 + tid;
        const int* sp; int eb;
        if (e < e1)      { sp = s0p; eb = 0; }
        else if (e < e2) { sp = s1p; eb = e1; }
        else if (e < e3) { sp = s2p; eb = e2; }
        else if (e < e4) { sp = s3p; eb = e3; }
        else             { sp = s4p; eb = e4; }
        int el = e - eb;
        int b = g >> BSHIFT;
        int pos = base[b] + atomicSub(&cnt[b], 1) - 1;
        edata[pos] = make_int2(sp[el] | ((g & 31) << 16), el);
    }
}

// Phase B: per-bucket exact placement. Read bucket region, scatter to exact
// per-node ranks in LDS, write back coalesced (strips node bits).
__global__ __launch_bounds__(256) void binB_kernel(
    const int* __restrict__ starts, int ntot, int2* __restrict__ edata) {
    __shared__ int ncur[32];
    __shared__ int2 stage[STAGE_CAP];
    int b = blockIdx.x, tid = threadIdx.x;
    int n0 = b << BSHIFT;
    int bstart = starts[n0];
    int bend = (b == NBUCK - 1) ? ntot : starts[n0 + 32];
    int cnt = bend - bstart;
    if (tid < 32) ncur[tid] = starts[n0 + tid] - bstart;
    __syncthreads();
    for (int i = tid; i < cnt; i += 256) {
        int2 r = edata[bstart + i];
        int l = (r.x >> 16) & 31;
        int rank = atomicAdd(&ncur[l], 1);
        stage[rank] = make_int2(r.x & 0xffff, r.y);
    }
    __syncthreads();
    for (int i = tid; i < cnt; i += 256)
        edata[bstart + i] = stage[i];
}

// One wave per dst node. 4 groups x 16 lanes; 8 edge chains in flight per
// group per iteration (32 edges/wave/iter). Lane gl holds dims gl*8..+7;
// ef dim gl. edata/ef read non-temporally (stream-once; keep feats cached).
__global__ __launch_bounds__(256) void agg_all_kernel(
    const u16* __restrict__ opb, const u16* __restrict__ devb,
    const float* __restrict__ ef0, const float* __restrict__ ef1,
    const float* __restrict__ ef2, const float* __restrict__ ef3,
    const float* __restrict__ ef4,
    const int2* __restrict__ edata, const int* __restrict__ starts,
    const int* __restrict__ deg, u16* __restrict__ agg) {
    int wl = (blockIdx.x * 256 + threadIdx.x) >> 6;
    int w = (wl < N_DEV) ? (NB3 + wl)
                         : ((wl - N_DEV < NB3) ? (wl - N_DEV) : wl);
    int lane = threadIdx.x & 63;
    int grp = lane >> 4, gl = lane & 15;
    const u16* sf; const float* efp;
    if (w < NB1)      { sf = devb; efp = ef0; }
    else if (w < NB2) { sf = opb;  efp = ef1; }
    else if (w < NB3) { sf = opb;  efp = ef2; }
    else if (w < NB4) { sf = opb;  efp = ef3; }
    else              { sf = devb; efp = ef4; }
    int s0 = starts[w], dg = deg[w];
    float2 a0 = {0.f, 0.f}, a1 = {0.f, 0.f}, a2 = {0.f, 0.f}, a3 = {0.f, 0.f};
    float aef = 0.f;
    for (int bb = 0; bb < dg; bb += 32) {
        int sx[8], ey[8];
#pragma unroll
        for (int k = 0; k < 8; k++) {
            int idx = bb + k * 4 + grp;
            sx[k] = 0; ey[k] = -1;
            if (idx < dg) {
                long long r = __builtin_nontemporal_load(
                    (const long long*)&edata[s0 + idx]);
                sx[k] = (int)(r & 0xffffffffLL);
                ey[k] = (int)(r >> 32);
            }
        }
#pragma unroll
        for (int k = 0; k < 8; k++) {
            if (ey[k] >= 0) {
                u32x4 f = *(const u32x4*)&sf[(size_t)sx[k] * 128 + gl * 8];
                a0.x += __uint_as_float(f[0] << 16);
                a0.y += __uint_as_float(f[0] & 0xffff0000u);
                a1.x += __uint_as_float(f[1] << 16);
                a1.y += __uint_as_float(f[1] & 0xffff0000u);
                a2.x += __uint_as_float(f[2] << 16);
                a2.y += __uint_as_float(f[2] & 0xffff0000u);
                a3.x += __uint_as_float(f[3] << 16);
                a3.y += __uint_as_float(f[3] & 0xffff0000u);
                aef  += __builtin_nontemporal_load(&efp[(size_t)ey[k] * 16 + gl]);
            }
        }
    }
#define RED(x) x += __shfl_xor(x, 16); x += __shfl_xor(x, 32);
    RED(a0.x) RED(a0.y) RED(a1.x) RED(a1.y)
    RED(a2.x) RED(a2.y) RED(a3.x) RED(a3.y) RED(aef)
#undef RED
    float inv = (dg > 0) ? 1.f / (float)dg : 0.f;
    u16* row = &agg[(size_t)w * 160];
    if (lane < 16) {
        u16x8 o;
        o[0] = bf16rn(a0.x * inv); o[1] = bf16rn(a0.y * inv);
        o[2] = bf16rn(a1.x * inv); o[3] = bf16rn(a1.y * inv);
        o[4] = bf16rn(a2.x * inv); o[5] = bf16rn(a2.y * inv);
        o[6] = bf16rn(a3.x * inv); o[7] = bf16rn(a3.y * inv);
        *(u16x8*)&row[gl * 8] = o;
        row[128 + gl] = bf16rn(aef * inv);
    } else if (lane < 32) {
        int g2 = lane - 16;
        row[144 + g2] = (g2 == 0 && dg > 0) ? (u16)0x3F80 : (u16)0;
    }
}

// bf16 MFMA GEMM: block = 4 waves, 64 rows x 128 cols. Wave holds 16 rows,
// 8 col-tiles (acc f32x4 x8). Epilogue relu(acc*scale); bias via K=144 slot.
__global__ __launch_bounds__(256) void gemm_mfma_kernel(
    const u16* __restrict__ aggb, const u16* __restrict__ wtop,
    const u16* __restrict__ wtdev, float* __restrict__ out, int opblocks) {
    int bid = blockIdx.x, tid = threadIdx.x;
    int wave = tid >> 6, lane = tid & 63;
    bool isop = bid < opblocks;
    int rowbase, ndst, nseg, outrow0, Kpad, sb0, sb1, sb2;
    const u16* Wt; float scale;
    if (isop) {
        rowbase = bid * 64; ndst = N_OP; nseg = 3; outrow0 = 0;
        Kpad = 480; Wt = wtop; scale = 1.f / 3.f;
        sb0 = NB1; sb1 = NB2; sb2 = NB4;
    } else {
        rowbase = (bid - opblocks) * 64; ndst = N_DEV; nseg = 2; outrow0 = N_OP;
        Kpad = 320; Wt = wtdev; scale = 0.5f;
        sb0 = NB0; sb1 = NB3; sb2 = NB3;
    }
    int r16 = rowbase + wave * 16 + (lane & 15);
    int ar = min(r16, ndst - 1);
    int kq = (lane >> 4) * 8;
    f32x4 acc[8];
#pragma unroll
    for (int nt = 0; nt < 8; nt++) acc[nt] = (f32x4){0.f, 0.f, 0.f, 0.f};

    const u16* wbase = Wt + (size_t)(lane & 15) * Kpad + kq;
    for (int seg = 0; seg < nseg; seg++) {
        int segbase = (seg == 0) ? sb0 : ((seg == 1) ? sb1 : sb2);
        const u16* ap = aggb + (size_t)(segbase + ar) * 160 + kq;
        const u16* wp = wbase + seg * 160;
        for (int k0 = 0; k0 < 160; k0 += 32) {
            short8 a = *(const short8*)(ap + k0);
#pragma unroll
            for (int nt = 0; nt < 8; nt++) {
                short8 b = *(const short8*)(wp + (size_t)nt * 16 * Kpad + k0);
                acc[nt] = __builtin_amdgcn_mfma_f32_16x16x32_bf16(a, b, acc[nt], 0, 0, 0);
            }
        }
    }

    int colb = lane & 15;
    int rowe = rowbase + wave * 16 + (lane >> 4) * 4;
#pragma unroll
    for (int nt = 0; nt < 8; nt++) {
#pragma unroll
        for (int r = 0; r < 4; r++) {
            int row = rowe + r;
            if (row < ndst)
                out[(size_t)(outrow0 + row) * 256 + 128 + nt * 16 + colb] =
                    fmaxf(acc[nt][r] * scale, 0.f);
        }
    }
}

extern "C" void kernel_launch(void* const* d_in, const int* in_sizes, int n_in,
                              void* d_out, int out_size, void* d_ws, size_t ws_size,
                              hipStream_t stream) {
    const float* opf  = (const float*)d_in[0];
    const float* devf = (const float*)d_in[1];
    const float* ef[5]; const int* src[5]; const int* dst[5];
    const float* W[5]; const float* bias[5];
    int ne[5];
    for (int i = 0; i < 5; i++) {
        ef[i]   = (const float*)d_in[2 + 5 * i + 0];
        src[i]  = (const int*)  d_in[2 + 5 * i + 1];
        dst[i]  = (const int*)  d_in[2 + 5 * i + 2];
        W[i]    = (const float*)d_in[2 + 5 * i + 3];
        bias[i] = (const float*)d_in[2 + 5 * i + 4];
        ne[i]   = in_sizes[2 + 5 * i + 1];
    }
    int e1 = ne[0], e2 = e1 + ne[1], e3 = e2 + ne[2], e4 = e3 + ne[3];
    int ntot = e4 + ne[4];
    int ntot_pad = (ntot + 1) & ~1;

    char* wp = (char*)d_ws;
    int* deg    = (int*)wp;  wp += (size_t)N_NODES * 4;
    int* starts = (int*)wp;  wp += (size_t)N_NODES * 4;
    int* cursor = (int*)wp;  wp += (size_t)NBUCK * 4;
    int* bsums  = (int*)wp;  wp += 256;
    int2* edata = (int2*)wp; wp += (size_t)ntot_pad * 8;
    u16* aggb   = (u16*)wp;  wp += (size_t)N_NODES * 160 * 2;
    u16* opb    = (u16*)wp;  wp += (size_t)N_OP * 128 * 2;
    u16* devb   = (u16*)wp;  wp += (size_t)N_DEV * 128 * 2;
    u16* wtop   = (u16*)wp;  wp += (size_t)128 * 480 * 2;
    u16* wtdev  = (u16*)wp;
    float* out  = (float*)d_out;

    zero_int_kernel<<<(N_NODES + 255) / 256, 256, 0, stream>>>(deg, N_NODES);

    const int NU = (N_OP + N_DEV) * 48 + 128 * 800;  // conv+copy+wt units
    prep_kernel<<<(NU + ntot + 255) / 256, 256, 0, stream>>>(
        opf, devf, W[0], W[1], W[2], W[3], W[4],
        bias[0], bias[1], bias[2], bias[3], bias[4],
        dst[0], dst[1], dst[2], dst[3], dst[4],
        e1, e2, e3, e4, ntot, opb, devb, out, wtop, wtdev, deg);

    const int nchunks = (N_NODES + 4095) / 4096;  // 40
    scan_block_kernel<<<nchunks, 256, 0, stream>>>(deg, starts, bsums, N_NODES);
    scan_bsums_kernel<<<1, 64, 0, stream>>>(bsums, nchunks);
    scan_add_kernel<<<(N_NODES + 255) / 256, 256, 0, stream>>>(starts, cursor, bsums, N_NODES);

    binA_kernel<<<(ntot + CHUNK - 1) / CHUNK, 256, 0, stream>>>(
        src[0], src[1], src[2], src[3], src[4],
        dst[0], dst[1], dst[2], dst[3], dst[4],
        e1, e2, e3, e4, ntot, cursor, edata);

    binB_kernel<<<NBUCK, 256, 0, stream>>>(starts, ntot, edata);

    agg_all_kernel<<<N_NODES / 4, 256, 0, stream>>>(
        opb, devb, ef[0], ef[1], ef[2], ef[3], ef[4], edata, starts, deg, aggb);

    int opblocks = (N_OP + 63) / 64, devblocks = (N_DEV + 63) / 64;
    gemm_mfma_kernel<<<opblocks + devblocks, 256, 0, stream>>>(
        aggb, wtop, wtdev, out, opblocks);
    (void)n_in; (void)out_size; (void)ws_size;
}

// Round 6
// 397.896 us; speedup vs baseline: 2.0762x; 1.0262x over previous
//
#include <hip/hip_runtime.h>

// ---------------------------------------------------------------------------
// GConv via  mean_e(concat(x_src, ef) @ W + b) = mean_feats @ W + mask*b
// zero -> prep(conv bf16 + copy left [one pass] + Wt build + degree count) ->
// scan(3, cursor init folded) -> binA (bucket runs) ->
// agg_fused (bucket stage in LDS + per-node gather, bf16 means) ->
// bf16 MFMA GEMM (op K=480, dev K=320), bias folded into K=144 slot.
// ---------------------------------------------------------------------------

#define N_OP    50000
#define N_DEV   5000
#define N_NODES 160000
#define NB0 0
#define NB1 5000
#define NB2 55000
#define NB3 105000
#define NB4 110000

#define NBUCK   5000     // 32 nodes per bucket
#define BSHIFT  5
#define CHUNK   8192     // edges per binA block
#define STAGE_CAP 4992   // max records per bucket (place worst ~3.9k; +17 sigma)

typedef unsigned short u16;
typedef unsigned int   u32;
typedef __attribute__((ext_vector_type(8))) unsigned short u16x8;
typedef __attribute__((ext_vector_type(4))) unsigned int   u32x4;
typedef __attribute__((ext_vector_type(8))) short          short8;
typedef __attribute__((ext_vector_type(4))) float          f32x4;

__device__ __forceinline__ u16 bf16rn(float x) {
    unsigned u = __float_as_uint(x);
    return (u16)((u + 0x7fffu + ((u >> 16) & 1u)) >> 16);
}

__global__ void zero_int_kernel(int* __restrict__ p, int n) {
    int i = blockIdx.x * 256 + threadIdx.x;
    if (i < n) p[i] = 0;
}

// Fused: feats->bf16 + copy left half of out (single pass), build Wt (bf16,
// transposed, bias folded at k=144), degree count.
__global__ __launch_bounds__(256) void prep_kernel(
    const float* __restrict__ opf, const float* __restrict__ devf,
    const float* __restrict__ W0, const float* __restrict__ W1,
    const float* __restrict__ W2, const float* __restrict__ W3,
    const float* __restrict__ W4,
    const float* __restrict__ B0, const float* __restrict__ B1,
    const float* __restrict__ B2, const float* __restrict__ B3,
    const float* __restrict__ B4,
    const int* __restrict__ d0, const int* __restrict__ d1,
    const int* __restrict__ d2, const int* __restrict__ d3,
    const int* __restrict__ d4,
    int e1, int e2, int e3, int e4, int ntot,
    u16* __restrict__ opb, u16* __restrict__ devb,
    float* __restrict__ out, u16* __restrict__ wtop, u16* __restrict__ wtdev,
    int* __restrict__ deg) {
    const int NU0 = (N_OP + N_DEV) * 16;   // conv+copy units (8 elems)
    const int NU2 = 128 * 480 + 128 * 320; // wt elems
    int t = blockIdx.x * 256 + threadIdx.x;
    if (t < NU0) {
        int row = t >> 4, q = t & 15;
        const float* s; u16* d; size_t lrow;
        if (row < N_OP) { s = opf;  d = opb;  lrow = (size_t)row; }
        else            { s = devf; d = devb; lrow = (size_t)(row - N_OP); }
        size_t off = lrow * 128 + q * 8;
        float4 x = *(const float4*)&s[off];
        float4 y = *(const float4*)&s[off + 4];
        u16x8 o;
        o[0] = bf16rn(x.x); o[1] = bf16rn(x.y); o[2] = bf16rn(x.z); o[3] = bf16rn(x.w);
        o[4] = bf16rn(y.x); o[5] = bf16rn(y.y); o[6] = bf16rn(y.z); o[7] = bf16rn(y.w);
        *(u16x8*)&d[off] = o;
        float* po = &out[(size_t)row * 256 + q * 8];
        *(float4*)po = x;
        *(float4*)(po + 4) = y;
        return;
    }
    t -= NU0;
    if (t < NU2) {
        if (t < 128 * 480) {   // wtop: segs prev, succ, serve
            int n = t / 480, kk = t % 480, seg = kk / 160, k = kk % 160;
            const float* Ws = (seg == 0) ? W1 : ((seg == 1) ? W2 : W4);
            const float* Bs = (seg == 0) ? B1 : ((seg == 1) ? B2 : B4);
            float v = (k < 144) ? Ws[(size_t)k * 128 + n] : ((k == 144) ? Bs[n] : 0.f);
            wtop[(size_t)n * 480 + kk] = bf16rn(v);
        } else {               // wtdev: segs link, place
            int q = t - 128 * 480;
            int n = q / 320, kk = q % 320, seg = kk / 160, k = kk % 160;
            const float* Ws = seg ? W3 : W0;
            const float* Bs = seg ? B3 : B0;
            float v = (k < 144) ? Ws[(size_t)k * 128 + n] : ((k == 144) ? Bs[n] : 0.f);
            wtdev[(size_t)n * 320 + kk] = bf16rn(v);
        }
        return;
    }
    t -= NU2;
    if (t >= ntot) return;
    const int* dp; int nb, eb;
    if (t < e1)      { dp = d0; nb = NB0; eb = 0; }
    else if (t < e2) { dp = d1; nb = NB1; eb = e1; }
    else if (t < e3) { dp = d2; nb = NB2; eb = e2; }
    else if (t < e4) { dp = d3; nb = NB3; eb = e3; }
    else             { dp = d4; nb = NB4; eb = e4; }
    atomicAdd(&deg[nb + dp[t - eb]], 1);
}

__global__ __launch_bounds__(256) void scan_block_kernel(
    const int* __restrict__ deg, int* __restrict__ starts,
    int* __restrict__ bsums, int n) {
    __shared__ int wsum[4];
    int tid = threadIdx.x;
    int base = blockIdx.x * 4096 + tid * 16;
    int v[16];
    int s = 0;
#pragma unroll
    for (int i = 0; i < 16; i++) {
        int idx = base + i;
        int t = (idx < n) ? deg[idx] : 0;
        v[i] = t; s += t;
    }
    int lane = tid & 63, wid = tid >> 6;
    int incl = s;
#pragma unroll
    for (int off = 1; off < 64; off <<= 1) {
        int t = __shfl_up(incl, off, 64);
        if (lane >= off) incl += t;
    }
    if (lane == 63) wsum[wid] = incl;
    __syncthreads();
    int woff = 0;
    for (int w2 = 0; w2 < wid; w2++) woff += wsum[w2];
    int run = woff + incl - s;
#pragma unroll
    for (int i = 0; i < 16; i++) {
        int idx = base + i;
        if (idx < n) starts[idx] = run;
        run += v[i];
    }
    if (tid == 255) bsums[blockIdx.x] = woff + incl;
}

__global__ void scan_bsums_kernel(int* __restrict__ bsums, int nb) {
    int lane = threadIdx.x;
    int v = (lane < nb) ? bsums[lane] : 0;
    int incl = v;
#pragma unroll
    for (int off = 1; off < 64; off <<= 1) {
        int t = __shfl_up(incl, off, 64);
        if (lane >= off) incl += t;
    }
    if (lane < nb) bsums[lane] = incl - v;
}

__global__ void scan_add_kernel(int* __restrict__ starts, int* __restrict__ cursor,
                                const int* __restrict__ bsums, int n) {
    int i = blockIdx.x * 256 + threadIdx.x;
    if (i < n) {
        int v = starts[i] + bsums[i >> 12];
        starts[i] = v;
        if ((i & 31) == 0) cursor[i >> BSHIFT] = v;   // bucket base
    }
}

// Phase A: bin edges into 32-node buckets; records land inside the bucket's
// final CSR region (arbitrary order within bucket). Record packs
// (src | nodeLocal<<16, edge_local). One global atomic per (block,bucket).
__global__ __launch_bounds__(256) void binA_kernel(
    const int* __restrict__ s0p, const int* __restrict__ s1p,
    const int* __restrict__ s2p, const int* __restrict__ s3p,
    const int* __restrict__ s4p,
    const int* __restrict__ d0, const int* __restrict__ d1,
    const int* __restrict__ d2, const int* __restrict__ d3,
    const int* __restrict__ d4,
    int e1, int e2, int e3, int e4, int ntot,
    int* __restrict__ cursor, int2* __restrict__ edata) {
    __shared__ int cnt[NBUCK];
    __shared__ int base[NBUCK];
    int tid = threadIdx.x;
    int e0 = blockIdx.x * CHUNK;
    for (int i = tid; i < NBUCK; i += 256) cnt[i] = 0;
    __syncthreads();
    int myg[32];
#pragma unroll 4
    for (int j = 0; j < 32; j++) {
        int e = e0 + j * 256 + tid;
        int g = -1;
        if (e < ntot) {
            const int* dp; int nb, eb;
            if (e < e1)      { dp = d0; nb = NB0; eb = 0; }
            else if (e < e2) { dp = d1; nb = NB1; eb = e1; }
            else if (e < e3) { dp = d2; nb = NB2; eb = e2; }
            else if (e < e4) { dp = d3; nb = NB3; eb = e3; }
            else             { dp = d4; nb = NB4; eb = e4; }
            g = nb + dp[e - eb];
            atomicAdd(&cnt[g >> BSHIFT], 1);
        }
        myg[j] = g;
    }
    __syncthreads();
    for (int b = tid; b < NBUCK; b += 256) {
        int c = cnt[b];
        base[b] = c ? atomicAdd(&cursor[b], c) : 0;
    }
    __syncthreads();
#pragma unroll 4
    for (int j = 0; j < 32; j++) {
        int g = myg[j];
        if (g < 0) continue;
        int e = e0 + j * 256 + tid;
        const int* sp; int eb;
        if (e < e1)      { sp = s0p; eb = 0; }
        else if (e < e2) { sp = s1p; eb = e1; }
        else if (e < e3) { sp = s2p; eb = e2; }
        else if (e < e4) { sp = s3p; eb = e3; }
        else             { sp = s4p; eb = e4; }
        int el = e - eb;
        int b = g >> BSHIFT;
        int pos = base[b] + atomicSub(&cnt[b], 1) - 1;
        edata[pos] = make_int2(sp[el] | ((g & 31) << 16), el);
    }
}

// Fused binB+agg: one block per bucket. Stage the bucket's records into LDS
// at exact per-node ranks, then 4 waves x 8 nodes each gather feats/ef with
// 4-group x 8-chain ILP. Heavy (place,link) buckets launched first.
__global__ __launch_bounds__(256) void agg_fused_kernel(
    const u16* __restrict__ opb, const u16* __restrict__ devb,
    const float* __restrict__ ef0, const float* __restrict__ ef1,
    const float* __restrict__ ef2, const float* __restrict__ ef3,
    const float* __restrict__ ef4,
    const int2* __restrict__ edata, const int* __restrict__ starts,
    const int* __restrict__ deg, int ntot, u16* __restrict__ agg) {
    __shared__ u16 s_src[STAGE_CAP];
    __shared__ int s_e[STAGE_CAP];
    __shared__ int ncur[32];
    int bid = blockIdx.x, tid = threadIdx.x;
    // bijective remap: place buckets (3281..3437) first, link (0..156) next
    int b;
    if (bid < 157)      b = 3281 + bid;
    else if (bid < 314) b = bid - 157;
    else { int t = bid - 314 + 157; b = (t >= 3281) ? t + 157 : t; }
    int n0 = b << BSHIFT;
    int bstart = starts[n0];
    int bend = (b == NBUCK - 1) ? ntot : starts[n0 + 32];
    int cnt = bend - bstart;
    if (tid < 32) ncur[tid] = starts[n0 + tid] - bstart;
    __syncthreads();
    for (int i = tid; i < cnt; i += 256) {
        long long rr = __builtin_nontemporal_load(
            (const long long*)&edata[bstart + i]);
        int x = (int)(rr & 0xffffffffLL);
        int e = (int)(rr >> 32);
        int l = (x >> 16) & 31;
        int rank = atomicAdd(&ncur[l], 1);
        s_src[rank] = (u16)(x & 0xffff);
        s_e[rank] = e;
    }
    __syncthreads();
    int wave = tid >> 6, lane = tid & 63;
    int grp = lane >> 4, gl = lane & 15;
    for (int ni = 0; ni < 8; ni++) {
        int w = n0 + wave * 8 + ni;
        const u16* sf; const float* efp;
        if (w < NB1)      { sf = devb; efp = ef0; }
        else if (w < NB2) { sf = opb;  efp = ef1; }
        else if (w < NB3) { sf = opb;  efp = ef2; }
        else if (w < NB4) { sf = opb;  efp = ef3; }
        else              { sf = devb; efp = ef4; }
        int dg = deg[w];
        int lo = starts[w] - bstart;
        float2 a0 = {0.f, 0.f}, a1 = {0.f, 0.f}, a2 = {0.f, 0.f}, a3 = {0.f, 0.f};
        float aef = 0.f;
        for (int bb = 0; bb < dg; bb += 32) {
            int sx[8], ey[8];
#pragma unroll
            for (int k = 0; k < 8; k++) {
                int idx = bb + k * 4 + grp;
                sx[k] = 0; ey[k] = -1;
                if (idx < dg) {
                    sx[k] = s_src[lo + idx];
                    ey[k] = s_e[lo + idx];
                }
            }
#pragma unroll
            for (int k = 0; k < 8; k++) {
                if (ey[k] >= 0) {
                    u32x4 f = *(const u32x4*)&sf[(size_t)sx[k] * 128 + gl * 8];
                    a0.x += __uint_as_float(f[0] << 16);
                    a0.y += __uint_as_float(f[0] & 0xffff0000u);
                    a1.x += __uint_as_float(f[1] << 16);
                    a1.y += __uint_as_float(f[1] & 0xffff0000u);
                    a2.x += __uint_as_float(f[2] << 16);
                    a2.y += __uint_as_float(f[2] & 0xffff0000u);
                    a3.x += __uint_as_float(f[3] << 16);
                    a3.y += __uint_as_float(f[3] & 0xffff0000u);
                    aef  += __builtin_nontemporal_load(&efp[(size_t)ey[k] * 16 + gl]);
                }
            }
        }
#define RED(x) x += __shfl_xor(x, 16); x += __shfl_xor(x, 32);
        RED(a0.x) RED(a0.y) RED(a1.x) RED(a1.y)
        RED(a2.x) RED(a2.y) RED(a3.x) RED(a3.y) RED(aef)
#undef RED
        float inv = (dg > 0) ? 1.f / (float)dg : 0.f;
        u16* row = &agg[(size_t)w * 160];
        if (lane < 16) {
            u16x8 o;
            o[0] = bf16rn(a0.x * inv); o[1] = bf16rn(a0.y * inv);
            o[2] = bf16rn(a1.x * inv); o[3] = bf16rn(a1.y * inv);
            o[4] = bf16rn(a2.x * inv); o[5] = bf16rn(a2.y * inv);
            o[6] = bf16rn(a3.x * inv); o[7] = bf16rn(a3.y * inv);
            *(u16x8*)&row[gl * 8] = o;
            row[128 + gl] = bf16rn(aef * inv);
        } else if (lane < 32) {
            int g2 = lane - 16;
            row[144 + g2] = (g2 == 0 && dg > 0) ? (u16)0x3F80 : (u16)0;
        }
    }
}

// bf16 MFMA GEMM: block = 4 waves, 64 rows x 128 cols. Wave holds 16 rows,
// 8 col-tiles (acc f32x4 x8). Epilogue relu(acc*scale); bias via K=144 slot.
__global__ __launch_bounds__(256) void gemm_mfma_kernel(
    const u16* __restrict__ aggb, const u16* __restrict__ wtop,
    const u16* __restrict__ wtdev, float* __restrict__ out, int opblocks) {
    int bid = blockIdx.x, tid = threadIdx.x;
    int wave = tid >> 6, lane = tid & 63;
    bool isop = bid < opblocks;
    int rowbase, ndst, nseg, outrow0, Kpad, sb0, sb1, sb2;
    const u16* Wt; float scale;
    if (isop) {
        rowbase = bid * 64; ndst = N_OP; nseg = 3; outrow0 = 0;
        Kpad = 480; Wt = wtop; scale = 1.f / 3.f;
        sb0 = NB1; sb1 = NB2; sb2 = NB4;
    } else {
        rowbase = (bid - opblocks) * 64; ndst = N_DEV; nseg = 2; outrow0 = N_OP;
        Kpad = 320; Wt = wtdev; scale = 0.5f;
        sb0 = NB0; sb1 = NB3; sb2 = NB3;
    }
    int r16 = rowbase + wave * 16 + (lane & 15);
    int ar = min(r16, ndst - 1);
    int kq = (lane >> 4) * 8;
    f32x4 acc[8];
#pragma unroll
    for (int nt = 0; nt < 8; nt++) acc[nt] = (f32x4){0.f, 0.f, 0.f, 0.f};

    const u16* wbase = Wt + (size_t)(lane & 15) * Kpad + kq;
    for (int seg = 0; seg < nseg; seg++) {
        int segbase = (seg == 0) ? sb0 : ((seg == 1) ? sb1 : sb2);
        const u16* ap = aggb + (size_t)(segbase + ar) * 160 + kq;
        const u16* wp = wbase + seg * 160;
        for (int k0 = 0; k0 < 160; k0 += 32) {
            short8 a = *(const short8*)(ap + k0);
#pragma unroll
            for (int nt = 0; nt < 8; nt++) {
                short8 b = *(const short8*)(wp + (size_t)nt * 16 * Kpad + k0);
                acc[nt] = __builtin_amdgcn_mfma_f32_16x16x32_bf16(a, b, acc[nt], 0, 0, 0);
            }
        }
    }

    int colb = lane & 15;
    int rowe = rowbase + wave * 16 + (lane >> 4) * 4;
#pragma unroll
    for (int nt = 0; nt < 8; nt++) {
#pragma unroll
        for (int r = 0; r < 4; r++) {
            int row = rowe + r;
            if (row < ndst)
                out[(size_t)(outrow0 + row) * 256 + 128 + nt * 16 + colb] =
                    fmaxf(acc[nt][r] * scale, 0.f);
        }
    }
}

extern "C" void kernel_launch(void* const* d_in, const int* in_sizes, int n_in,
                              void* d_out, int out_size, void* d_ws, size_t ws_size,
                              hipStream_t stream) {
    const float* opf  = (const float*)d_in[0];
    const float* devf = (const float*)d_in[1];
    const float* ef[5]; const int* src[5]; const int* dst[5];
    const float* W[5]; const float* bias[5];
    int ne[5];
    for (int i = 0; i < 5; i++) {
        ef[i]   = (const float*)d_in[2 + 5 * i + 0];
        src[i]  = (const int*)  d_in[2 + 5 * i + 1];
        dst[i]  = (const int*)  d_in[2 + 5 * i + 2];
        W[i]    = (const float*)d_in[2 + 5 * i + 3];
        bias[i] = (const float*)d_in[2 + 5 * i + 4];
        ne[i]   = in_sizes[2 + 5 * i + 1];
    }
    int e1 = ne[0], e2 = e1 + ne[1], e3 = e2 + ne[2], e4 = e3 + ne[3];
    int ntot = e4 + ne[4];
    int ntot_pad = (ntot + 1) & ~1;

    char* wp = (char*)d_ws;
    int* deg    = (int*)wp;  wp += (size_t)N_NODES * 4;
    int* starts = (int*)wp;  wp += (size_t)N_NODES * 4;
    int* cursor = (int*)wp;  wp += (size_t)NBUCK * 4;
    int* bsums  = (int*)wp;  wp += 256;
    int2* edata = (int2*)wp; wp += (size_t)ntot_pad * 8;
    u16* aggb   = (u16*)wp;  wp += (size_t)N_NODES * 160 * 2;
    u16* opb    = (u16*)wp;  wp += (size_t)N_OP * 128 * 2;
    u16* devb   = (u16*)wp;  wp += (size_t)N_DEV * 128 * 2;
    u16* wtop   = (u16*)wp;  wp += (size_t)128 * 480 * 2;
    u16* wtdev  = (u16*)wp;
    float* out  = (float*)d_out;

    zero_int_kernel<<<(N_NODES + 255) / 256, 256, 0, stream>>>(deg, N_NODES);

    const int NU = (N_OP + N_DEV) * 16 + 128 * 800;  // conv+copy, wt units
    prep_kernel<<<(NU + ntot + 255) / 256, 256, 0, stream>>>(
        opf, devf, W[0], W[1], W[2], W[3], W[4],
        bias[0], bias[1], bias[2], bias[3], bias[4],
        dst[0], dst[1], dst[2], dst[3], dst[4],
        e1, e2, e3, e4, ntot, opb, devb, out, wtop, wtdev, deg);

    const int nchunks = (N_NODES + 4095) / 4096;  // 40
    scan_block_kernel<<<nchunks, 256, 0, stream>>>(deg, starts, bsums, N_NODES);
    scan_bsums_kernel<<<1, 64, 0, stream>>>(bsums, nchunks);
    scan_add_kernel<<<(N_NODES + 255) / 256, 256, 0, stream>>>(starts, cursor, bsums, N_NODES);

    binA_kernel<<<(ntot + CHUNK - 1) / CHUNK, 256, 0, stream>>>(
        src[0], src[1], src[2], src[3], src[4],
        dst[0], dst[1], dst[2], dst[3], dst[4],
        e1, e2, e3, e4, ntot, cursor, edata);

    agg_fused_kernel<<<NBUCK, 256, 0, stream>>>(
        opb, devb, ef[0], ef[1], ef[2], ef[3], ef[4],
        edata, starts, deg, ntot, aggb);

    int opblocks = (N_OP + 63) / 64, devblocks = (N_DEV + 63) / 64;
    gemm_mfma_kernel<<<opblocks + devblocks, 256, 0, stream>>>(
        aggb, wtop, wtdev, out, opblocks);
    (void)n_in; (void)out_size; (void)ws_size;
}